// Round 17
// baseline (418.534 us; speedup 1.0000x reference)
//
#include <hip/hip_runtime.h>
#include <hip/hip_bf16.h>

using bf16 = __hip_bfloat16;

#define NN 16384
#define NE 262144
#define ET (NE + NN)
#define NB 128
#define FEAT 78
#define HEADS 10
#define D1 780
#define OD 128
#define PL 1000
#define VOC 26
#define SLOPE 0.2f

typedef __attribute__((ext_vector_type(8))) short short8;
typedef __attribute__((ext_vector_type(4))) float f32x4;

static __device__ __forceinline__ ushort f2bf(float f){
    bf16 h = __float2bfloat16(f);
    return *reinterpret_cast<ushort*>(&h);
}
static __device__ __forceinline__ float bf2f(ushort u){
    bf16 h;
    *reinterpret_cast<ushort*>(&h) = u;
    return __bfloat162float(h);
}

// ---------------- CSR build ----------------
__global__ void k_hist(const int* __restrict__ ei, int* __restrict__ cnt){
    int e = blockIdx.x*256 + threadIdx.x;
    if (e >= ET) return;
    int dst = (e < NE) ? ei[NE + e] : (e - NE);
    atomicAdd(&cnt[dst], 1);
}

__global__ __launch_bounds__(1024) void k_scan(const int* __restrict__ cnt, int* __restrict__ off){
    __shared__ int ps[1024];
    int t = threadIdx.x;
    int loc[16]; int s = 0;
#pragma unroll
    for (int j = 0; j < 16; ++j){ loc[j] = cnt[t*16 + j]; s += loc[j]; }
    ps[t] = s; __syncthreads();
    for (int d = 1; d < 1024; d <<= 1){
        int v = (t >= d) ? ps[t - d] : 0;
        __syncthreads();
        ps[t] += v;
        __syncthreads();
    }
    int run = (t == 0) ? 0 : ps[t - 1];
#pragma unroll
    for (int j = 0; j < 16; ++j){ off[t*16 + j] = run; run += loc[j]; }
    if (t == 1023) off[NN] = run;
}

__global__ void k_fill(const int* __restrict__ ei, const int* __restrict__ off,
                       int* __restrict__ cur, int* __restrict__ csrc, int* __restrict__ cdst){
    int e = blockIdx.x*256 + threadIdx.x;
    if (e >= ET) return;
    int src, dst;
    if (e < NE){ src = ei[e]; dst = ei[NE + e]; } else { src = e - NE; dst = src; }
    int p = off[dst] + atomicAdd(&cur[dst], 1);
    csrc[p] = src;
    cdst[p] = dst;
}

// ---------------- GAT layer 1 (x-space) ----------------
__global__ __launch_bounds__(256) void k_alpha1x(const float* __restrict__ x, const float* __restrict__ W1,
                                                 const float* __restrict__ asw, const float* __restrict__ adw,
                                                 float* __restrict__ as1, float* __restrict__ ad1){
    __shared__ float xs[64*79];
    __shared__ float va[D1], vd[D1];
    int n0 = blockIdx.x * 64, t = threadIdx.x;
    for (int i = t; i < 64*FEAT; i += 256){
        int n = i / FEAT, k = i % FEAT;
        xs[n*79 + k] = x[(size_t)n0*FEAT + i];
    }
    for (int idx = t; idx < D1; idx += 256){
        int h = idx / FEAT, k = idx % FEAT;
        const float* wr = W1 + (size_t)k*D1 + h*FEAT;
        const float* pa = asw + h*FEAT;
        const float* pd = adw + h*FEAT;
        float a = 0.f, d = 0.f;
        for (int j = 0; j < FEAT; ++j){ float w = wr[j]; a += w*pa[j]; d += w*pd[j]; }
        va[idx] = a; vd[idx] = d;
    }
    __syncthreads();
    for (int p = t; p < 64*HEADS; p += 256){
        int h = p >> 6, nl = p & 63;
        const float* xr = xs + nl*79;
        const float* pa = va + h*FEAT; const float* pd = vd + h*FEAT;
        float a = 0.f, d = 0.f;
        for (int k = 0; k < FEAT; ++k){ float xv = xr[k]; a += xv*pa[k]; d += xv*pd[k]; }
        as1[(size_t)(n0 + nl)*HEADS + h] = a;
        ad1[(size_t)(n0 + nl)*HEADS + h] = d;
    }
}

// edge-parallel leaky logits for layer 1 (CSR order -> contiguous reads downstream)
__global__ __launch_bounds__(256) void k_edge1(const float* __restrict__ as1, const float* __restrict__ ad1,
                                               const int* __restrict__ csrc, const int* __restrict__ cdst,
                                               float* __restrict__ e1){
    int e = blockIdx.x*256 + threadIdx.x;
    if (e >= ET) return;
    int s = csrc[e], d = cdst[e];
#pragma unroll
    for (int h = 0; h < HEADS; ++h){
        float v = as1[(size_t)s*HEADS + h] + ad1[(size_t)d*HEADS + h];
        e1[(size_t)e*HEADS + h] = v > 0.f ? v : SLOPE*v;
    }
}

// per dst (64-thread block): contiguous e1 logits; chunk-register staged f32 gather; bf16 agg out
__global__ __launch_bounds__(64) void k_gat1x(const float* __restrict__ x, const float* __restrict__ e1,
                                              const int* __restrict__ off, const int* __restrict__ csrc,
                                              ushort* __restrict__ aggh){
    int dst = blockIdx.x, lane = threadIdx.x;
    int beg = off[dst], end = off[dst + 1];
    int deg = end - beg;
    int s0 = 0;
    float p[HEADS], mx[HEADS];
#pragma unroll
    for (int h = 0; h < HEADS; ++h){ mx[h] = -1e30f; p[h] = 0.f; }
    if (lane < deg){
        s0 = csrc[beg + lane];
        const float* er = e1 + (size_t)(beg + lane)*HEADS;
#pragma unroll
        for (int h = 0; h < HEADS; ++h){ p[h] = er[h]; mx[h] = er[h]; }
    }
    if (deg > 64){
        for (int e = beg + 64 + lane; e < end; e += 64){
            const float* er = e1 + (size_t)e*HEADS;
#pragma unroll
            for (int h = 0; h < HEADS; ++h) mx[h] = fmaxf(mx[h], er[h]);
        }
    }
#pragma unroll
    for (int h = 0; h < HEADS; ++h)
        for (int o = 32; o; o >>= 1) mx[h] = fmaxf(mx[h], __shfl_xor(mx[h], o));
    float sm[HEADS];
#pragma unroll
    for (int h = 0; h < HEADS; ++h) sm[h] = 0.f;
    if (lane < deg){
#pragma unroll
        for (int h = 0; h < HEADS; ++h){ p[h] = __expf(p[h] - mx[h]); sm[h] = p[h]; }
    }
    if (deg > 64){
        for (int e = beg + 64 + lane; e < end; e += 64){
            const float* er = e1 + (size_t)e*HEADS;
#pragma unroll
            for (int h = 0; h < HEADS; ++h) sm[h] += __expf(er[h] - mx[h]);
        }
    }
    float inv[HEADS];
#pragma unroll
    for (int h = 0; h < HEADS; ++h){
        for (int o = 32; o; o >>= 1) sm[h] += __shfl_xor(sm[h], o);
        inv[h] = 1.f/(sm[h] + 1e-16f);
        p[h] = (lane < deg) ? p[h]*inv[h] : 0.f;
    }
    float acc1[HEADS], acc2[HEADS];
#pragma unroll
    for (int h = 0; h < HEADS; ++h){ acc1[h] = 0.f; acc2[h] = 0.f; }
    int cnt0 = deg < 64 ? deg : 64;
    for (int c0 = 0; c0 < cnt0; c0 += 16){
        float r1[16], r2[16];
#pragma unroll
        for (int i = 0; i < 16; ++i){
            int s = __shfl(s0, c0 + i);
            const float* xr = x + (size_t)s*FEAT;
            r1[i] = xr[lane];
            r2[i] = (lane < FEAT - 64) ? xr[64 + lane] : 0.f;
        }
#pragma unroll
        for (int i = 0; i < 16; ++i){
            if (c0 + i < cnt0){
#pragma unroll
                for (int h = 0; h < HEADS; ++h){
                    float al = __shfl(p[h], c0 + i);
                    acc1[h] += al*r1[i];
                    acc2[h] += al*r2[i];
                }
            }
        }
    }
    if (deg > 64){
        for (int base = beg + 64; base < end; base += 64){
            int cnt = min(64, end - base);
            int s1 = 0;
            float pp[HEADS];
#pragma unroll
            for (int h = 0; h < HEADS; ++h) pp[h] = 0.f;
            if (lane < cnt){
                s1 = csrc[base + lane];
                const float* er = e1 + (size_t)(base + lane)*HEADS;
#pragma unroll
                for (int h = 0; h < HEADS; ++h)
                    pp[h] = __expf(er[h] - mx[h])*inv[h];
            }
            for (int c0 = 0; c0 < cnt; c0 += 16){
                float r1[16], r2[16];
#pragma unroll
                for (int i = 0; i < 16; ++i){
                    int s = __shfl(s1, c0 + i);
                    const float* xr = x + (size_t)s*FEAT;
                    r1[i] = xr[lane];
                    r2[i] = (lane < FEAT - 64) ? xr[64 + lane] : 0.f;
                }
#pragma unroll
                for (int i = 0; i < 16; ++i){
                    if (c0 + i < cnt){
#pragma unroll
                        for (int h = 0; h < HEADS; ++h){
                            float al = __shfl(pp[h], c0 + i);
                            acc1[h] += al*r1[i];
                            acc2[h] += al*r2[i];
                        }
                    }
                }
            }
        }
    }
#pragma unroll
    for (int h = 0; h < HEADS; ++h)
        aggh[(size_t)dst*D1 + h*FEAT + lane] = f2bf(acc1[h]);
    if (lane < FEAT - 64){
#pragma unroll
        for (int h = 0; h < HEADS; ++h)
            aggh[(size_t)dst*D1 + h*FEAT + 64 + lane] = f2bf(acc2[h]);
    }
}

// block = (head, node-tile-64): bf16 agg in, bf16 h1 out
__global__ __launch_bounds__(256) void k_post1(const ushort* __restrict__ aggh, const float* __restrict__ W1,
                                               const float* __restrict__ b1, ushort* __restrict__ h1h){
    __shared__ float w1s[FEAT][80];
    __shared__ float ags[64][81];
    __shared__ float bsh[FEAT];
    int ht = blockIdx.x >> 8;
    int nt = blockIdx.x & 255;
    int n0 = nt * 64;
    int t = threadIdx.x;
    for (int i = t; i < FEAT*FEAT; i += 256){
        int k = i / FEAT, j = i % FEAT;
        w1s[k][j] = W1[(size_t)k*D1 + ht*FEAT + j];
    }
    for (int i = t; i < 64*FEAT; i += 256){
        int r = i / FEAT, k = i % FEAT;
        ags[r][k] = bf2f(aggh[(size_t)(n0 + r)*D1 + ht*FEAT + k]);
    }
    if (t < FEAT) bsh[t] = b1[ht*FEAT + t];
    __syncthreads();
    if (t < 208){
        int rg = t / 13, cg = t % 13;
        int c0 = cg*6;
        float acc[4][6];
#pragma unroll
        for (int i = 0; i < 4; ++i)
#pragma unroll
            for (int j = 0; j < 6; ++j) acc[i][j] = 0.f;
        for (int k = 0; k < FEAT; ++k){
            float av[4];
#pragma unroll
            for (int i = 0; i < 4; ++i) av[i] = ags[rg*4 + i][k];
            float2 w01 = *(const float2*)&w1s[k][c0];
            float2 w23 = *(const float2*)&w1s[k][c0 + 2];
            float2 w45 = *(const float2*)&w1s[k][c0 + 4];
            float wv[6] = {w01.x, w01.y, w23.x, w23.y, w45.x, w45.y};
#pragma unroll
            for (int i = 0; i < 4; ++i)
#pragma unroll
                for (int j = 0; j < 6; ++j) acc[i][j] += av[i]*wv[j];
        }
#pragma unroll
        for (int i = 0; i < 4; ++i){
#pragma unroll
            for (int j = 0; j < 6; ++j){
                float v = acc[i][j] + bsh[c0 + j];
                v = v > 0.f ? v : __expf(v) - 1.f;   // ELU
                h1h[(size_t)(n0 + rg*4 + i)*D1 + ht*FEAT + c0 + j] = f2bf(v);
            }
        }
    }
}

// W2 -> bf16 once
__global__ __launch_bounds__(256) void k_w2h(const float* __restrict__ w2, ushort* __restrict__ w2h){
    int i = blockIdx.x*256 + threadIdx.x;
    w2h[i] = f2bf(w2[i]);
}

// ---------------- GAT layer 2 GEMM via MFMA, fused alpha2 ----------------
__global__ __launch_bounds__(256) void k_gemm2m(const ushort* __restrict__ h1h, const ushort* __restrict__ w2h,
                                                const float* __restrict__ s2w, const float* __restrict__ d2w,
                                                float* __restrict__ xl2,
                                                float* __restrict__ as2, float* __restrict__ ad2){
    __shared__ ushort As[64][40];
    __shared__ ushort Bs[128][40];
    int r0 = blockIdx.x * 64;
    int t = threadIdx.x;
    int w = t >> 6, l = t & 63;
    f32x4 acc[8];
#pragma unroll
    for (int i = 0; i < 8; ++i) acc[i] = (f32x4){0.f, 0.f, 0.f, 0.f};
    for (int k0 = 0; k0 < D1; k0 += 32){
        {
            int r = t >> 2, kq = (t & 3)*8;
            int gk = k0 + kq;
            ushort tmp[8];
            if (gk + 8 <= D1){
                *(ushort4*)&tmp[0] = *(const ushort4*)&h1h[(size_t)(r0 + r)*D1 + gk];
                *(ushort4*)&tmp[4] = *(const ushort4*)&h1h[(size_t)(r0 + r)*D1 + gk + 4];
            } else {
#pragma unroll
                for (int j = 0; j < 8; ++j)
                    tmp[j] = (gk + j < D1) ? h1h[(size_t)(r0 + r)*D1 + gk + j] : (ushort)0;
            }
            *(ushort4*)&As[r][kq]     = *(ushort4*)&tmp[0];
            *(ushort4*)&As[r][kq + 4] = *(ushort4*)&tmp[4];
        }
        {
            int n8 = (t & 15)*8, kk = t >> 4;
#pragma unroll
            for (int half = 0; half < 2; ++half){
                int k = kk + half*16;
                ushort tmp[8];
                if (k0 + k < D1){
                    *(uint4*)&tmp[0] = *(const uint4*)&w2h[(size_t)(k0 + k)*OD + n8];
                } else {
#pragma unroll
                    for (int j = 0; j < 8; ++j) tmp[j] = 0;
                }
#pragma unroll
                for (int j = 0; j < 8; ++j) Bs[n8 + j][k] = tmp[j];
            }
        }
        __syncthreads();
        short8 a = *(const short8*)&As[w*16 + (l & 15)][(l >> 4)*8];
#pragma unroll
        for (int nt = 0; nt < 8; ++nt){
            short8 b = *(const short8*)&Bs[nt*16 + (l & 15)][(l >> 4)*8];
            acc[nt] = __builtin_amdgcn_mfma_f32_16x16x32_bf16(a, b, acc[nt], 0, 0, 0);
        }
        __syncthreads();
    }
    int colg = l & 15, kg = l >> 4;
    float sa[4] = {0.f,0.f,0.f,0.f}, sd[4] = {0.f,0.f,0.f,0.f};
#pragma unroll
    for (int nt = 0; nt < 8; ++nt){
        int c = nt*16 + colg;
        float wsv = s2w[c], wdv = d2w[c];
#pragma unroll
        for (int r = 0; r < 4; ++r){
            float v = acc[nt][r];
            int row = r0 + w*16 + kg*4 + r;
            xl2[(size_t)row*OD + c] = v;
            sa[r] += v*wsv; sd[r] += v*wdv;
        }
    }
#pragma unroll
    for (int r = 0; r < 4; ++r){
#pragma unroll
        for (int o = 8; o; o >>= 1){ sa[r] += __shfl_xor(sa[r], o); sd[r] += __shfl_xor(sd[r], o); }
    }
    if (colg == 0){
        int row = r0 + w*16 + kg*4;
#pragma unroll
        for (int r = 0; r < 4; ++r){ as2[row + r] = sa[r]; ad2[row + r] = sd[r]; }
    }
}

// edge-parallel logits for layer 2
__global__ __launch_bounds__(256) void k_edge2(const float* __restrict__ as2, const float* __restrict__ ad2,
                                               const int* __restrict__ csrc, const int* __restrict__ cdst,
                                               float* __restrict__ e2){
    int e = blockIdx.x*256 + threadIdx.x;
    if (e >= ET) return;
    float v = as2[csrc[e]] + ad2[cdst[e]];
    e2[e] = v > 0.f ? v : SLOPE*v;
}

// per dst (64-thread block): contiguous e2 logits; chunk-staged f32 gather
__global__ __launch_bounds__(64) void k_gat2(const float* __restrict__ xl2, const float* __restrict__ e2,
                                             const int* __restrict__ off, const int* __restrict__ csrc,
                                             const float* __restrict__ b2, float* __restrict__ h2){
    int dst = blockIdx.x, lane = threadIdx.x;
    int beg = off[dst], end = off[dst + 1];
    int deg = end - beg;
    int s0 = 0; float v0 = -1e30f;
    if (lane < deg){
        s0 = csrc[beg + lane];
        v0 = e2[beg + lane];
    }
    float m = v0;
    if (deg > 64){
        for (int e = beg + 64 + lane; e < end; e += 64)
            m = fmaxf(m, e2[e]);
    }
    for (int o = 32; o; o >>= 1) m = fmaxf(m, __shfl_xor(m, o));
    float pe = (lane < deg) ? __expf(v0 - m) : 0.f;
    float sm = pe;
    if (deg > 64){
        for (int e = beg + 64 + lane; e < end; e += 64)
            sm += __expf(e2[e] - m);
    }
    for (int o = 32; o; o >>= 1) sm += __shfl_xor(sm, o);
    float inv = 1.f / (sm + 1e-16f);
    float p = pe * inv;
    float a0 = 0.f, a1 = 0.f;
    int cnt0 = deg < 64 ? deg : 64;
    for (int c0 = 0; c0 < cnt0; c0 += 16){
        float r1[16], r2[16];
#pragma unroll
        for (int i = 0; i < 16; ++i){
            int s = __shfl(s0, c0 + i);
            r1[i] = xl2[(size_t)s*OD + lane];
            r2[i] = xl2[(size_t)s*OD + 64 + lane];
        }
#pragma unroll
        for (int i = 0; i < 16; ++i){
            if (c0 + i < cnt0){
                float al = __shfl(p, c0 + i);
                a0 += al*r1[i];
                a1 += al*r2[i];
            }
        }
    }
    if (deg > 64){
        for (int base = beg + 64; base < end; base += 64){
            int cnt = min(64, end - base);
            int s1 = 0; float pp = 0.f;
            if (lane < cnt){
                s1 = csrc[base + lane];
                pp = __expf(e2[base + lane] - m) * inv;
            }
            for (int c0 = 0; c0 < cnt; c0 += 16){
                float r1[16], r2[16];
#pragma unroll
                for (int i = 0; i < 16; ++i){
                    int s = __shfl(s1, c0 + i);
                    r1[i] = xl2[(size_t)s*OD + lane];
                    r2[i] = xl2[(size_t)s*OD + 64 + lane];
                }
#pragma unroll
                for (int i = 0; i < 16; ++i){
                    if (c0 + i < cnt){
                        float al = __shfl(pp, c0 + i);
                        a0 += al*r1[i];
                        a1 += al*r2[i];
                    }
                }
            }
        }
    }
    float o0 = a0 + b2[lane];      o0 = o0 > 0.f ? o0 : 0.f;
    float o1 = a1 + b2[64 + lane]; o1 = o1 > 0.f ? o1 : 0.f;
    h2[(size_t)dst*OD + lane] = o0;
    h2[(size_t)dst*OD + 64 + lane] = o1;
}

// ---------------- pooling + graph FC (fused) ----------------
__global__ __launch_bounds__(128) void k_poolfc(const float* __restrict__ h2, const int* __restrict__ batch,
                                                const float* __restrict__ w, const float* __restrict__ bias,
                                                float* __restrict__ gfc){
    __shared__ float row[OD];
    int b = blockIdx.x, t = threadIdx.x;
    int lo = 0, hi = NN;
    while (lo < hi){ int mid = (lo + hi) >> 1; if (batch[mid] < b) lo = mid + 1; else hi = mid; }
    int s0 = lo;
    lo = s0; hi = NN;
    while (lo < hi){ int mid = (lo + hi) >> 1; if (batch[mid] < b + 1) lo = mid + 1; else hi = mid; }
    int s1 = lo;
    float mx = 0.f;
    for (int n = s0; n < s1; ++n) mx = fmaxf(mx, h2[(size_t)n*OD + t]);
    row[t] = mx;
    __syncthreads();
    float acc = 0.f;
    for (int k = 0; k < OD; ++k) acc += row[k] * w[k*OD + t];
    acc += bias[t];
    gfc[b*OD + t] = acc > 0.f ? acc : 0.f;
}

// ---------------- protein branch ----------------
__global__ __launch_bounds__(256) void k_wt(const float* __restrict__ convw, float* __restrict__ wt){
    int idx = blockIdx.x*256 + threadIdx.x;
    int i = idx >> 8, ok = idx & 255;
    wt[idx] = convw[(size_t)(ok >> 3)*PL*8 + (size_t)i*8 + (ok & 7)];
}

__global__ __launch_bounds__(256) void k_abuild(const int* __restrict__ target, const float* __restrict__ wt,
                                                float* __restrict__ Ag){
    __shared__ int Ai[VOC][256];
    __shared__ int tss[256];
    int b = blockIdx.x >> 2, seg = blockIdx.x & 3;
    int t = threadIdx.x;
#pragma unroll
    for (int v = 0; v < VOC; ++v) Ai[v][t] = 0;
    if (t < 250) tss[t] = target[b*PL + seg*250 + t];
    __syncthreads();
    const float* wtb = wt + (size_t)(seg*250)*256 + t;
    const float SC = 16777216.0f;               // 2^24
    for (int i = 0; i < 250; ++i){
        float w = wtb[(size_t)i*256];
        int q = __float2int_rn(w * SC);
        atomicAdd(&Ai[tss[i]][t], q);
    }
    __syncthreads();
    const float INV = 5.9604644775390625e-08f;  // 2^-24
    float* Ao = Ag + (size_t)blockIdx.x*VOC*256 + t;
#pragma unroll
    for (int v = 0; v < VOC; ++v) Ao[(size_t)v*256] = (float)Ai[v][t] * INV;
}

__global__ __launch_bounds__(256) void k_conv(const float* __restrict__ Ag, const float* __restrict__ emb,
                                              const float* __restrict__ convb, float* __restrict__ cbuf){
    __shared__ float As[VOC][128];
    __shared__ float embs[VOC*128 + 16];
    int b = blockIdx.x >> 1, half = blockIdx.x & 1;
    int t = threadIdx.x;
    for (int i = t; i < VOC*128; i += 256){
        int v = i >> 7, c = i & 127;
        float s = 0.f;
#pragma unroll
        for (int seg = 0; seg < 4; ++seg)
            s += Ag[((size_t)(b*4 + seg)*VOC + v)*256 + half*128 + c];
        As[v][c] = s;
        embs[i] = emb[i];
    }
    if (t < 16) embs[VOC*128 + t] = 0.f;
    __syncthreads();
    int o_l = t >> 4, pg = t & 15, p0 = pg * 8;
    float accp[8];
#pragma unroll
    for (int i = 0; i < 8; ++i) accp[i] = 0.f;
    for (int v = 0; v < VOC; ++v){
        float w[15];
        const float* er = embs + v*128 + p0;
#pragma unroll
        for (int i = 0; i < 15; ++i) w[i] = er[i];
#pragma unroll
        for (int k2 = 0; k2 < 8; ++k2){
            float a = As[v][o_l*8 + k2];
#pragma unroll
            for (int j = 0; j < 8; ++j) accp[j] += a * w[j + k2];
        }
    }
    float cbv = convb[half*16 + o_l];
#pragma unroll
    for (int j = 0; j < 8; ++j){
        int p = p0 + j;
        if (p < 121){
            float v2 = accp[j] + cbv;
            cbuf[(size_t)b*3872 + (half*16 + o_l)*121 + p] = v2 > 0.f ? v2 : 0.f;
        }
    }
}

__global__ __launch_bounds__(256) void k_xt(const float* __restrict__ cbuf, const float* __restrict__ fxw,
                                            float* __restrict__ xtp){
    __shared__ float csh[16][242];
    int kt = blockIdx.x >> 3, bt = blockIdx.x & 7;
    int t = threadIdx.x;
    for (int i = t; i < 16*242; i += 256){
        int bb = i / 242, kk = i % 242;
        csh[bb][kk] = cbuf[(size_t)(bt*16 + bb)*3872 + kt*242 + kk];
    }
    __syncthreads();
    int j = t & 127, bh = t >> 7;
    float acc[8];
#pragma unroll
    for (int i = 0; i < 8; ++i) acc[i] = 0.f;
    for (int kk = 0; kk < 242; ++kk){
        float w = fxw[(size_t)(kt*242 + kk)*128 + j];
#pragma unroll
        for (int bb = 0; bb < 8; ++bb) acc[bb] += csh[bh*8 + bb][kk] * w;
    }
#pragma unroll
    for (int bb = 0; bb < 8; ++bb)
        xtp[(size_t)kt*NB*128 + (size_t)(bt*16 + bh*8 + bb)*128 + j] = acc[bb];
}

// ---------------- head: fc1 (512 blocks), fc2 partials (512), reduce+out (128) ----------------
__global__ __launch_bounds__(256) void k_fc1(const float* __restrict__ gfc, const float* __restrict__ xtp,
                                             const float* __restrict__ fxb,
                                             const float* __restrict__ w, const float* __restrict__ bias,
                                             float* __restrict__ out){
    __shared__ float xc[256];
    int b = blockIdx.x >> 2, nt = blockIdx.x & 3;
    int t = threadIdx.x;
    if (t < 128) xc[t] = gfc[b*OD + t];
    else {
        int j = t - 128;
        float s = fxb[j];
#pragma unroll
        for (int kt = 0; kt < 16; ++kt) s += xtp[(size_t)kt*NB*128 + (size_t)b*128 + j];
        xc[t] = s;
    }
    __syncthreads();
    int j = nt*256 + t;
    float acc = 0.f;
    for (int k = 0; k < 256; ++k) acc += xc[k] * w[(size_t)k*1024 + j];
    acc += bias[j];
    out[b*1024 + j] = acc > 0.f ? acc : 0.f;
}

__global__ __launch_bounds__(256) void k_fc2p(const float* __restrict__ hf1, const float* __restrict__ w,
                                              float* __restrict__ part){
    __shared__ float row[256];
    int b = blockIdx.x >> 2, ks = blockIdx.x & 3;
    int t = threadIdx.x;
    row[t] = hf1[b*1024 + ks*256 + t];
    __syncthreads();
    float acc = 0.f;
    const float* wc = w + (size_t)(ks*256)*256 + t;
    for (int k = 0; k < 256; ++k) acc += row[k] * wc[(size_t)k*256];
    part[((size_t)ks*NB + b)*256 + t] = acc;
}

__global__ __launch_bounds__(256) void k_fc2red(const float* __restrict__ part, const float* __restrict__ bias,
                                                const float* __restrict__ ow, const float* __restrict__ ob,
                                                float* __restrict__ out){
    __shared__ float s2[256];
    int b = blockIdx.x, t = threadIdx.x;
    float v = part[(size_t)b*256 + t] + part[((size_t)NB + b)*256 + t]
            + part[((size_t)2*NB + b)*256 + t] + part[((size_t)3*NB + b)*256 + t];
    v += bias[t];
    v = v > 0.f ? v : 0.f;
    s2[t] = v * ow[t];
    __syncthreads();
    if (t < 64){
        float a = s2[t] + s2[t + 64] + s2[t + 128] + s2[t + 192];
#pragma unroll
        for (int o = 32; o; o >>= 1) a += __shfl_xor(a, o);
        if (t == 0) out[b] = a + ob[0];
    }
}

extern "C" void kernel_launch(void* const* d_in, const int* in_sizes, int n_in,
                              void* d_out, int out_size, void* d_ws, size_t ws_size,
                              hipStream_t stream){
    const float* x    = (const float*)d_in[0];
    const int*  ei    = (const int*)d_in[1];
    const int*  batch = (const int*)d_in[2];
    const int*  target= (const int*)d_in[3];
    const float* W1   = (const float*)d_in[4];
    const float* as1w = (const float*)d_in[5];
    const float* ad1w = (const float*)d_in[6];
    const float* b1   = (const float*)d_in[7];
    const float* W2   = (const float*)d_in[8];
    const float* as2w = (const float*)d_in[9];
    const float* ad2w = (const float*)d_in[10];
    const float* b2   = (const float*)d_in[11];
    const float* fgw  = (const float*)d_in[12];
    const float* fgb  = (const float*)d_in[13];
    const float* emb  = (const float*)d_in[14];
    const float* cw   = (const float*)d_in[15];
    const float* cb   = (const float*)d_in[16];
    const float* fxw  = (const float*)d_in[17];
    const float* fxb  = (const float*)d_in[18];
    const float* f1w  = (const float*)d_in[19];
    const float* f1b  = (const float*)d_in[20];
    const float* f2w  = (const float*)d_in[21];
    const float* f2b  = (const float*)d_in[22];
    const float* ow   = (const float*)d_in[23];
    const float* ob   = (const float*)d_in[24];

    float* f = (float*)d_ws;
    size_t o = 0;
    float* aggf = f + o; o += (size_t)NN*D1;    // lower half: bf16 agg; upper half: e1
    float* h1f = f + o; o += (size_t)NN*D1;     // bf16 h1 (half used); reused as Ag after gemm2m
    float* as1 = f + o; o += (size_t)NN*HEADS;
    float* ad1 = f + o; o += (size_t)NN*HEADS;
    float* xl2 = f + o; o += (size_t)NN*OD;
    float* h2  = f + o; o += (size_t)NN*OD;
    float* as2 = f + o; o += NN;
    float* ad2 = f + o; o += NN;
    float* gfc = f + o; o += NB*OD;
    float* hf1 = f + o; o += NB*1024;
    float* part= f + o; o += (size_t)4*NB*256;
    float* wt  = f + o; o += (size_t)PL*256;
    float* cbuf= f + o; o += (size_t)NB*3872;
    float* xtp = f + o; o += (size_t)16*NB*128;
    float* w2hf= f + o; o += (size_t)D1*OD/2 + 64;
    float* e2  = f + o; o += ET;
    int* cnt   = (int*)(f + o); o += NN;
    int* off   = (int*)(f + o); o += NN + 1;
    int* csrc  = (int*)(f + o); o += ET;
    int* cdst  = (int*)(f + o); o += ET;
    ushort* aggh = (ushort*)aggf;                        // 25.5MB (half of aggf)
    float*  e1   = aggf + (size_t)NN*D1/2;               // upper half of aggf (11.1MB of 25.5MB)
    ushort* h1h  = (ushort*)h1f;
    ushort* w2h  = (ushort*)w2hf;
    float*  Ag   = h1f;                                   // h1h dead after gemm2m
    (void)ws_size; (void)in_sizes; (void)n_in; (void)out_size;

    // CSR by destination (+ per-edge dst)
    hipMemsetAsync(cnt, 0, NN*sizeof(int), stream);
    k_hist<<<(ET + 255)/256, 256, 0, stream>>>(ei, cnt);
    k_scan<<<1, 1024, 0, stream>>>(cnt, off);
    hipMemsetAsync(cnt, 0, NN*sizeof(int), stream);
    k_fill<<<(ET + 255)/256, 256, 0, stream>>>(ei, off, cnt, csrc, cdst);

    // GAT layer 1 in x-space
    k_alpha1x<<<NN/64, 256, 0, stream>>>(x, W1, as1w, ad1w, as1, ad1);
    k_edge1<<<(ET + 255)/256, 256, 0, stream>>>(as1, ad1, csrc, cdst, e1);
    k_gat1x<<<NN, 64, 0, stream>>>(x, e1, off, csrc, aggh);
    k_post1<<<HEADS*256, 256, 0, stream>>>(aggh, W1, b1, h1h);

    // GAT layer 2: MFMA GEMM + fused alpha2
    k_w2h<<<(D1*OD)/256, 256, 0, stream>>>(W2, w2h);
    k_gemm2m<<<NN/64, 256, 0, stream>>>(h1h, w2h, as2w, ad2w, xl2, as2, ad2);
    k_edge2<<<(ET + 255)/256, 256, 0, stream>>>(as2, ad2, csrc, cdst, e2);
    k_gat2<<<NN, 64, 0, stream>>>(xl2, e2, off, csrc, b2, h2);

    // pooling + graph fc (fused)
    k_poolfc<<<NB, 128, 0, stream>>>(h2, batch, fgw, fgb, gfc);

    // protein branch
    k_wt<<<1000, 256, 0, stream>>>(cw, wt);
    k_abuild<<<NB*4, 256, 0, stream>>>(target, wt, Ag);
    k_conv<<<NB*2, 256, 0, stream>>>(Ag, emb, cb, cbuf);
    k_xt<<<128, 256, 0, stream>>>(cbuf, fxw, xtp);

    // head (wide)
    k_fc1<<<NB*4, 256, 0, stream>>>(gfc, xtp, fxb, f1w, f1b, hf1);
    k_fc2p<<<NB*4, 256, 0, stream>>>(hf1, f2w, part);
    k_fc2red<<<NB, 256, 0, stream>>>(part, f2b, ow, ob, (float*)d_out);
}

// Round 18
// 398.829 us; speedup vs baseline: 1.0494x; 1.0494x over previous
//
#include <hip/hip_runtime.h>
#include <hip/hip_bf16.h>

using bf16 = __hip_bfloat16;

#define NN 16384
#define NE 262144
#define ET (NE + NN)
#define NB 128
#define FEAT 78
#define HEADS 10
#define D1 780
#define OD 128
#define PL 1000
#define VOC 26
#define SLOPE 0.2f

typedef __attribute__((ext_vector_type(8))) short short8;
typedef __attribute__((ext_vector_type(4))) float f32x4;

static __device__ __forceinline__ ushort f2bf(float f){
    bf16 h = __float2bfloat16(f);
    return *reinterpret_cast<ushort*>(&h);
}
static __device__ __forceinline__ float bf2f(ushort u){
    bf16 h;
    *reinterpret_cast<ushort*>(&h) = u;
    return __bfloat162float(h);
}

// ---------------- CSR build ----------------
__global__ void k_hist(const int* __restrict__ ei, int* __restrict__ cnt){
    int e = blockIdx.x*256 + threadIdx.x;
    if (e >= ET) return;
    int dst = (e < NE) ? ei[NE + e] : (e - NE);
    atomicAdd(&cnt[dst], 1);
}

__global__ __launch_bounds__(1024) void k_scan(const int* __restrict__ cnt, int* __restrict__ off){
    __shared__ int ps[1024];
    int t = threadIdx.x;
    int loc[16]; int s = 0;
#pragma unroll
    for (int j = 0; j < 16; ++j){ loc[j] = cnt[t*16 + j]; s += loc[j]; }
    ps[t] = s; __syncthreads();
    for (int d = 1; d < 1024; d <<= 1){
        int v = (t >= d) ? ps[t - d] : 0;
        __syncthreads();
        ps[t] += v;
        __syncthreads();
    }
    int run = (t == 0) ? 0 : ps[t - 1];
#pragma unroll
    for (int j = 0; j < 16; ++j){ off[t*16 + j] = run; run += loc[j]; }
    if (t == 1023) off[NN] = run;
}

__global__ void k_fill(const int* __restrict__ ei, const int* __restrict__ off,
                       int* __restrict__ cur, int* __restrict__ csrc){
    int e = blockIdx.x*256 + threadIdx.x;
    if (e >= ET) return;
    int src, dst;
    if (e < NE){ src = ei[e]; dst = ei[NE + e]; } else { src = e - NE; dst = src; }
    int p = off[dst] + atomicAdd(&cur[dst], 1);
    csrc[p] = src;
}

// ---------------- GAT layer 1 (x-space) ----------------
__global__ __launch_bounds__(256) void k_alpha1x(const float* __restrict__ x, const float* __restrict__ W1,
                                                 const float* __restrict__ asw, const float* __restrict__ adw,
                                                 float* __restrict__ as1, float* __restrict__ ad1){
    __shared__ float xs[64*79];
    __shared__ float va[D1], vd[D1];
    int n0 = blockIdx.x * 64, t = threadIdx.x;
    for (int i = t; i < 64*FEAT; i += 256){
        int n = i / FEAT, k = i % FEAT;
        xs[n*79 + k] = x[(size_t)n0*FEAT + i];
    }
    for (int idx = t; idx < D1; idx += 256){
        int h = idx / FEAT, k = idx % FEAT;
        const float* wr = W1 + (size_t)k*D1 + h*FEAT;
        const float* pa = asw + h*FEAT;
        const float* pd = adw + h*FEAT;
        float a = 0.f, d = 0.f;
        for (int j = 0; j < FEAT; ++j){ float w = wr[j]; a += w*pa[j]; d += w*pd[j]; }
        va[idx] = a; vd[idx] = d;
    }
    __syncthreads();
    for (int p = t; p < 64*HEADS; p += 256){
        int h = p >> 6, nl = p & 63;
        const float* xr = xs + nl*79;
        const float* pa = va + h*FEAT; const float* pd = vd + h*FEAT;
        float a = 0.f, d = 0.f;
        for (int k = 0; k < FEAT; ++k){ float xv = xr[k]; a += xv*pa[k]; d += xv*pd[k]; }
        as1[(size_t)(n0 + nl)*HEADS + h] = a;
        ad1[(size_t)(n0 + nl)*HEADS + h] = d;
    }
}

// per dst (64-thread block): lane-owned alpha; chunk-register staged f32 gather; bf16 agg out
__global__ __launch_bounds__(64) void k_gat1x(const float* __restrict__ x, const float* __restrict__ as1,
                                              const float* __restrict__ ad1, const int* __restrict__ off,
                                              const int* __restrict__ csrc,
                                              ushort* __restrict__ aggh){
    int dst = blockIdx.x, lane = threadIdx.x;
    int beg = off[dst], end = off[dst + 1];
    int deg = end - beg;
    float adh[HEADS];
#pragma unroll
    for (int h = 0; h < HEADS; ++h) adh[h] = ad1[(size_t)dst*HEADS + h];
    int s0 = 0;
    float p[HEADS], mx[HEADS];
#pragma unroll
    for (int h = 0; h < HEADS; ++h){ mx[h] = -1e30f; p[h] = 0.f; }
    if (lane < deg){
        s0 = csrc[beg + lane];
#pragma unroll
        for (int h = 0; h < HEADS; ++h){
            float v = as1[(size_t)s0*HEADS + h] + adh[h];
            v = v > 0.f ? v : SLOPE*v;
            p[h] = v; mx[h] = v;
        }
    }
    if (deg > 64){
        for (int e = beg + 64 + lane; e < end; e += 64){
            int s = csrc[e];
#pragma unroll
            for (int h = 0; h < HEADS; ++h){
                float v = as1[(size_t)s*HEADS + h] + adh[h];
                v = v > 0.f ? v : SLOPE*v;
                mx[h] = fmaxf(mx[h], v);
            }
        }
    }
#pragma unroll
    for (int h = 0; h < HEADS; ++h)
        for (int o = 32; o; o >>= 1) mx[h] = fmaxf(mx[h], __shfl_xor(mx[h], o));
    float sm[HEADS];
#pragma unroll
    for (int h = 0; h < HEADS; ++h) sm[h] = 0.f;
    if (lane < deg){
#pragma unroll
        for (int h = 0; h < HEADS; ++h){ p[h] = __expf(p[h] - mx[h]); sm[h] = p[h]; }
    }
    if (deg > 64){
        for (int e = beg + 64 + lane; e < end; e += 64){
            int s = csrc[e];
#pragma unroll
            for (int h = 0; h < HEADS; ++h){
                float v = as1[(size_t)s*HEADS + h] + adh[h];
                v = v > 0.f ? v : SLOPE*v;
                sm[h] += __expf(v - mx[h]);
            }
        }
    }
    float inv[HEADS];
#pragma unroll
    for (int h = 0; h < HEADS; ++h){
        for (int o = 32; o; o >>= 1) sm[h] += __shfl_xor(sm[h], o);
        inv[h] = 1.f/(sm[h] + 1e-16f);
        p[h] = (lane < deg) ? p[h]*inv[h] : 0.f;
    }
    float acc1[HEADS], acc2[HEADS];
#pragma unroll
    for (int h = 0; h < HEADS; ++h){ acc1[h] = 0.f; acc2[h] = 0.f; }
    int cnt0 = deg < 64 ? deg : 64;
    for (int c0 = 0; c0 < cnt0; c0 += 16){
        float r1[16], r2[16];
#pragma unroll
        for (int i = 0; i < 16; ++i){
            int s = __shfl(s0, c0 + i);
            const float* xr = x + (size_t)s*FEAT;
            r1[i] = xr[lane];
            r2[i] = (lane < FEAT - 64) ? xr[64 + lane] : 0.f;
        }
#pragma unroll
        for (int i = 0; i < 16; ++i){
            if (c0 + i < cnt0){
#pragma unroll
                for (int h = 0; h < HEADS; ++h){
                    float al = __shfl(p[h], c0 + i);
                    acc1[h] += al*r1[i];
                    acc2[h] += al*r2[i];
                }
            }
        }
    }
    if (deg > 64){
        for (int base = beg + 64; base < end; base += 64){
            int cnt = min(64, end - base);
            int s1 = 0;
            float pp[HEADS];
#pragma unroll
            for (int h = 0; h < HEADS; ++h) pp[h] = 0.f;
            if (lane < cnt){
                s1 = csrc[base + lane];
#pragma unroll
                for (int h = 0; h < HEADS; ++h){
                    float v = as1[(size_t)s1*HEADS + h] + adh[h];
                    v = v > 0.f ? v : SLOPE*v;
                    pp[h] = __expf(v - mx[h])*inv[h];
                }
            }
            for (int c0 = 0; c0 < cnt; c0 += 16){
                float r1[16], r2[16];
#pragma unroll
                for (int i = 0; i < 16; ++i){
                    int s = __shfl(s1, c0 + i);
                    const float* xr = x + (size_t)s*FEAT;
                    r1[i] = xr[lane];
                    r2[i] = (lane < FEAT - 64) ? xr[64 + lane] : 0.f;
                }
#pragma unroll
                for (int i = 0; i < 16; ++i){
                    if (c0 + i < cnt){
#pragma unroll
                        for (int h = 0; h < HEADS; ++h){
                            float al = __shfl(pp[h], c0 + i);
                            acc1[h] += al*r1[i];
                            acc2[h] += al*r2[i];
                        }
                    }
                }
            }
        }
    }
#pragma unroll
    for (int h = 0; h < HEADS; ++h)
        aggh[(size_t)dst*D1 + h*FEAT + lane] = f2bf(acc1[h]);
    if (lane < FEAT - 64){
#pragma unroll
        for (int h = 0; h < HEADS; ++h)
            aggh[(size_t)dst*D1 + h*FEAT + 64 + lane] = f2bf(acc2[h]);
    }
}

// block = (head, node-tile-64): bf16 agg in, bf16 h1 out
__global__ __launch_bounds__(256) void k_post1(const ushort* __restrict__ aggh, const float* __restrict__ W1,
                                               const float* __restrict__ b1, ushort* __restrict__ h1h){
    __shared__ float w1s[FEAT][80];
    __shared__ float ags[64][81];
    __shared__ float bsh[FEAT];
    int ht = blockIdx.x >> 8;
    int nt = blockIdx.x & 255;
    int n0 = nt * 64;
    int t = threadIdx.x;
    for (int i = t; i < FEAT*FEAT; i += 256){
        int k = i / FEAT, j = i % FEAT;
        w1s[k][j] = W1[(size_t)k*D1 + ht*FEAT + j];
    }
    for (int i = t; i < 64*FEAT; i += 256){
        int r = i / FEAT, k = i % FEAT;
        ags[r][k] = bf2f(aggh[(size_t)(n0 + r)*D1 + ht*FEAT + k]);
    }
    if (t < FEAT) bsh[t] = b1[ht*FEAT + t];
    __syncthreads();
    if (t < 208){
        int rg = t / 13, cg = t % 13;
        int c0 = cg*6;
        float acc[4][6];
#pragma unroll
        for (int i = 0; i < 4; ++i)
#pragma unroll
            for (int j = 0; j < 6; ++j) acc[i][j] = 0.f;
        for (int k = 0; k < FEAT; ++k){
            float av[4];
#pragma unroll
            for (int i = 0; i < 4; ++i) av[i] = ags[rg*4 + i][k];
            float2 w01 = *(const float2*)&w1s[k][c0];
            float2 w23 = *(const float2*)&w1s[k][c0 + 2];
            float2 w45 = *(const float2*)&w1s[k][c0 + 4];
            float wv[6] = {w01.x, w01.y, w23.x, w23.y, w45.x, w45.y};
#pragma unroll
            for (int i = 0; i < 4; ++i)
#pragma unroll
                for (int j = 0; j < 6; ++j) acc[i][j] += av[i]*wv[j];
        }
#pragma unroll
        for (int i = 0; i < 4; ++i){
#pragma unroll
            for (int j = 0; j < 6; ++j){
                float v = acc[i][j] + bsh[c0 + j];
                v = v > 0.f ? v : __expf(v) - 1.f;   // ELU
                h1h[(size_t)(n0 + rg*4 + i)*D1 + ht*FEAT + c0 + j] = f2bf(v);
            }
        }
    }
}

// ---------------- GAT layer 2 GEMM via MFMA, fused alpha2 ----------------
// B staged directly from f32 W2 with in-register bf16 convert (k_w2h deleted)
__global__ __launch_bounds__(256) void k_gemm2m(const ushort* __restrict__ h1h, const float* __restrict__ w2,
                                                const float* __restrict__ s2w, const float* __restrict__ d2w,
                                                float* __restrict__ xl2,
                                                float* __restrict__ as2, float* __restrict__ ad2){
    __shared__ ushort As[64][40];
    __shared__ ushort Bs[128][40];
    int r0 = blockIdx.x * 64;
    int t = threadIdx.x;
    int w = t >> 6, l = t & 63;
    f32x4 acc[8];
#pragma unroll
    for (int i = 0; i < 8; ++i) acc[i] = (f32x4){0.f, 0.f, 0.f, 0.f};
    for (int k0 = 0; k0 < D1; k0 += 32){
        {
            int r = t >> 2, kq = (t & 3)*8;
            int gk = k0 + kq;
            ushort tmp[8];
            if (gk + 8 <= D1){
                *(ushort4*)&tmp[0] = *(const ushort4*)&h1h[(size_t)(r0 + r)*D1 + gk];
                *(ushort4*)&tmp[4] = *(const ushort4*)&h1h[(size_t)(r0 + r)*D1 + gk + 4];
            } else {
#pragma unroll
                for (int j = 0; j < 8; ++j)
                    tmp[j] = (gk + j < D1) ? h1h[(size_t)(r0 + r)*D1 + gk + j] : (ushort)0;
            }
            *(ushort4*)&As[r][kq]     = *(ushort4*)&tmp[0];
            *(ushort4*)&As[r][kq + 4] = *(ushort4*)&tmp[4];
        }
        {
            int n8 = (t & 15)*8, kk = t >> 4;
#pragma unroll
            for (int half = 0; half < 2; ++half){
                int k = kk + half*16;
                ushort tmp[8];
                if (k0 + k < D1){
                    float4 f0 = *(const float4*)&w2[(size_t)(k0 + k)*OD + n8];
                    float4 f1 = *(const float4*)&w2[(size_t)(k0 + k)*OD + n8 + 4];
                    tmp[0] = f2bf(f0.x); tmp[1] = f2bf(f0.y); tmp[2] = f2bf(f0.z); tmp[3] = f2bf(f0.w);
                    tmp[4] = f2bf(f1.x); tmp[5] = f2bf(f1.y); tmp[6] = f2bf(f1.z); tmp[7] = f2bf(f1.w);
                } else {
#pragma unroll
                    for (int j = 0; j < 8; ++j) tmp[j] = 0;
                }
#pragma unroll
                for (int j = 0; j < 8; ++j) Bs[n8 + j][k] = tmp[j];
            }
        }
        __syncthreads();
        short8 a = *(const short8*)&As[w*16 + (l & 15)][(l >> 4)*8];
#pragma unroll
        for (int nt = 0; nt < 8; ++nt){
            short8 b = *(const short8*)&Bs[nt*16 + (l & 15)][(l >> 4)*8];
            acc[nt] = __builtin_amdgcn_mfma_f32_16x16x32_bf16(a, b, acc[nt], 0, 0, 0);
        }
        __syncthreads();
    }
    int colg = l & 15, kg = l >> 4;
    float sa[4] = {0.f,0.f,0.f,0.f}, sd[4] = {0.f,0.f,0.f,0.f};
#pragma unroll
    for (int nt = 0; nt < 8; ++nt){
        int c = nt*16 + colg;
        float wsv = s2w[c], wdv = d2w[c];
#pragma unroll
        for (int r = 0; r < 4; ++r){
            float v = acc[nt][r];
            int row = r0 + w*16 + kg*4 + r;
            xl2[(size_t)row*OD + c] = v;
            sa[r] += v*wsv; sd[r] += v*wdv;
        }
    }
#pragma unroll
    for (int r = 0; r < 4; ++r){
#pragma unroll
        for (int o = 8; o; o >>= 1){ sa[r] += __shfl_xor(sa[r], o); sd[r] += __shfl_xor(sd[r], o); }
    }
    if (colg == 0){
        int row = r0 + w*16 + kg*4;
#pragma unroll
        for (int r = 0; r < 4; ++r){ as2[row + r] = sa[r]; ad2[row + r] = sd[r]; }
    }
}

// per dst (64-thread block): lane-owned alpha, chunk-staged f32 gather
__global__ __launch_bounds__(64) void k_gat2(const float* __restrict__ xl2, const float* __restrict__ as2,
                                             const float* __restrict__ ad2, const int* __restrict__ off,
                                             const int* __restrict__ csrc, const float* __restrict__ b2,
                                             float* __restrict__ h2){
    int dst = blockIdx.x, lane = threadIdx.x;
    int beg = off[dst], end = off[dst + 1];
    int deg = end - beg;
    float ad = ad2[dst];
    int s0 = 0; float v0 = -1e30f;
    if (lane < deg){
        s0 = csrc[beg + lane];
        float v = as2[s0] + ad;
        v0 = v > 0.f ? v : SLOPE*v;
    }
    float m = v0;
    if (deg > 64){
        for (int e = beg + 64 + lane; e < end; e += 64){
            float v = as2[csrc[e]] + ad; v = v > 0.f ? v : SLOPE*v;
            m = fmaxf(m, v);
        }
    }
    for (int o = 32; o; o >>= 1) m = fmaxf(m, __shfl_xor(m, o));
    float pe = (lane < deg) ? __expf(v0 - m) : 0.f;
    float sm = pe;
    if (deg > 64){
        for (int e = beg + 64 + lane; e < end; e += 64){
            float v = as2[csrc[e]] + ad; v = v > 0.f ? v : SLOPE*v;
            sm += __expf(v - m);
        }
    }
    for (int o = 32; o; o >>= 1) sm += __shfl_xor(sm, o);
    float inv = 1.f / (sm + 1e-16f);
    float p = pe * inv;
    float a0 = 0.f, a1 = 0.f;
    int cnt0 = deg < 64 ? deg : 64;
    for (int c0 = 0; c0 < cnt0; c0 += 16){
        float r1[16], r2[16];
#pragma unroll
        for (int i = 0; i < 16; ++i){
            int s = __shfl(s0, c0 + i);
            r1[i] = xl2[(size_t)s*OD + lane];
            r2[i] = xl2[(size_t)s*OD + 64 + lane];
        }
#pragma unroll
        for (int i = 0; i < 16; ++i){
            if (c0 + i < cnt0){
                float al = __shfl(p, c0 + i);
                a0 += al*r1[i];
                a1 += al*r2[i];
            }
        }
    }
    if (deg > 64){
        for (int base = beg + 64; base < end; base += 64){
            int cnt = min(64, end - base);
            int s1 = 0; float pp = 0.f;
            if (lane < cnt){
                s1 = csrc[base + lane];
                float v = as2[s1] + ad; v = v > 0.f ? v : SLOPE*v;
                pp = __expf(v - m) * inv;
            }
            for (int c0 = 0; c0 < cnt; c0 += 16){
                float r1[16], r2[16];
#pragma unroll
                for (int i = 0; i < 16; ++i){
                    int s = __shfl(s1, c0 + i);
                    r1[i] = xl2[(size_t)s*OD + lane];
                    r2[i] = xl2[(size_t)s*OD + 64 + lane];
                }
#pragma unroll
                for (int i = 0; i < 16; ++i){
                    if (c0 + i < cnt){
                        float al = __shfl(pp, c0 + i);
                        a0 += al*r1[i];
                        a1 += al*r2[i];
                    }
                }
            }
        }
    }
    float o0 = a0 + b2[lane];      o0 = o0 > 0.f ? o0 : 0.f;
    float o1 = a1 + b2[64 + lane]; o1 = o1 > 0.f ? o1 : 0.f;
    h2[(size_t)dst*OD + lane] = o0;
    h2[(size_t)dst*OD + 64 + lane] = o1;
}

// ---------------- pooling + graph FC (fused) ----------------
__global__ __launch_bounds__(128) void k_poolfc(const float* __restrict__ h2, const int* __restrict__ batch,
                                                const float* __restrict__ w, const float* __restrict__ bias,
                                                float* __restrict__ gfc){
    __shared__ float row[OD];
    int b = blockIdx.x, t = threadIdx.x;
    int lo = 0, hi = NN;
    while (lo < hi){ int mid = (lo + hi) >> 1; if (batch[mid] < b) lo = mid + 1; else hi = mid; }
    int s0 = lo;
    lo = s0; hi = NN;
    while (lo < hi){ int mid = (lo + hi) >> 1; if (batch[mid] < b + 1) lo = mid + 1; else hi = mid; }
    int s1 = lo;
    float mx = 0.f;
    for (int n = s0; n < s1; ++n) mx = fmaxf(mx, h2[(size_t)n*OD + t]);
    row[t] = mx;
    __syncthreads();
    float acc = 0.f;
    for (int k = 0; k < OD; ++k) acc += row[k] * w[k*OD + t];
    acc += bias[t];
    gfc[b*OD + t] = acc > 0.f ? acc : 0.f;
}

// ---------------- protein branch ----------------
__global__ __launch_bounds__(256) void k_wt(const float* __restrict__ convw, float* __restrict__ wt){
    int idx = blockIdx.x*256 + threadIdx.x;
    int i = idx >> 8, ok = idx & 255;
    wt[idx] = convw[(size_t)(ok >> 3)*PL*8 + (size_t)i*8 + (ok & 7)];
}

__global__ __launch_bounds__(256) void k_abuild(const int* __restrict__ target, const float* __restrict__ wt,
                                                float* __restrict__ Ag){
    __shared__ int Ai[VOC][256];
    __shared__ int tss[256];
    int b = blockIdx.x >> 2, seg = blockIdx.x & 3;
    int t = threadIdx.x;
#pragma unroll
    for (int v = 0; v < VOC; ++v) Ai[v][t] = 0;
    if (t < 250) tss[t] = target[b*PL + seg*250 + t];
    __syncthreads();
    const float* wtb = wt + (size_t)(seg*250)*256 + t;
    const float SC = 16777216.0f;               // 2^24
    for (int i = 0; i < 250; ++i){
        float w = wtb[(size_t)i*256];
        int q = __float2int_rn(w * SC);
        atomicAdd(&Ai[tss[i]][t], q);
    }
    __syncthreads();
    const float INV = 5.9604644775390625e-08f;  // 2^-24
    float* Ao = Ag + (size_t)blockIdx.x*VOC*256 + t;
#pragma unroll
    for (int v = 0; v < VOC; ++v) Ao[(size_t)v*256] = (float)Ai[v][t] * INV;
}

__global__ __launch_bounds__(256) void k_conv(const float* __restrict__ Ag, const float* __restrict__ emb,
                                              const float* __restrict__ convb, float* __restrict__ cbuf){
    __shared__ float As[VOC][128];
    __shared__ float embs[VOC*128 + 16];
    int b = blockIdx.x >> 1, half = blockIdx.x & 1;
    int t = threadIdx.x;
    for (int i = t; i < VOC*128; i += 256){
        int v = i >> 7, c = i & 127;
        float s = 0.f;
#pragma unroll
        for (int seg = 0; seg < 4; ++seg)
            s += Ag[((size_t)(b*4 + seg)*VOC + v)*256 + half*128 + c];
        As[v][c] = s;
        embs[i] = emb[i];
    }
    if (t < 16) embs[VOC*128 + t] = 0.f;
    __syncthreads();
    int o_l = t >> 4, pg = t & 15, p0 = pg * 8;
    float accp[8];
#pragma unroll
    for (int i = 0; i < 8; ++i) accp[i] = 0.f;
    for (int v = 0; v < VOC; ++v){
        float w[15];
        const float* er = embs + v*128 + p0;
#pragma unroll
        for (int i = 0; i < 15; ++i) w[i] = er[i];
#pragma unroll
        for (int k2 = 0; k2 < 8; ++k2){
            float a = As[v][o_l*8 + k2];
#pragma unroll
            for (int j = 0; j < 8; ++j) accp[j] += a * w[j + k2];
        }
    }
    float cbv = convb[half*16 + o_l];
#pragma unroll
    for (int j = 0; j < 8; ++j){
        int p = p0 + j;
        if (p < 121){
            float v2 = accp[j] + cbv;
            cbuf[(size_t)b*3872 + (half*16 + o_l)*121 + p] = v2 > 0.f ? v2 : 0.f;
        }
    }
}

__global__ __launch_bounds__(256) void k_xt(const float* __restrict__ cbuf, const float* __restrict__ fxw,
                                            float* __restrict__ xtp){
    __shared__ float csh[16][242];
    int kt = blockIdx.x >> 3, bt = blockIdx.x & 7;
    int t = threadIdx.x;
    for (int i = t; i < 16*242; i += 256){
        int bb = i / 242, kk = i % 242;
        csh[bb][kk] = cbuf[(size_t)(bt*16 + bb)*3872 + kt*242 + kk];
    }
    __syncthreads();
    int j = t & 127, bh = t >> 7;
    float acc[8];
#pragma unroll
    for (int i = 0; i < 8; ++i) acc[i] = 0.f;
    for (int kk = 0; kk < 242; ++kk){
        float w = fxw[(size_t)(kt*242 + kk)*128 + j];
#pragma unroll
        for (int bb = 0; bb < 8; ++bb) acc[bb] += csh[bh*8 + bb][kk] * w;
    }
#pragma unroll
    for (int bb = 0; bb < 8; ++bb)
        xtp[(size_t)kt*NB*128 + (size_t)(bt*16 + bh*8 + bb)*128 + j] = acc[bb];
}

// ---------------- head: fc1 (512 blocks), fc2 partials (512), reduce+out (128) ----------------
__global__ __launch_bounds__(256) void k_fc1(const float* __restrict__ gfc, const float* __restrict__ xtp,
                                             const float* __restrict__ fxb,
                                             const float* __restrict__ w, const float* __restrict__ bias,
                                             float* __restrict__ out){
    __shared__ float xc[256];
    int b = blockIdx.x >> 2, nt = blockIdx.x & 3;
    int t = threadIdx.x;
    if (t < 128) xc[t] = gfc[b*OD + t];
    else {
        int j = t - 128;
        float s = fxb[j];
#pragma unroll
        for (int kt = 0; kt < 16; ++kt) s += xtp[(size_t)kt*NB*128 + (size_t)b*128 + j];
        xc[t] = s;
    }
    __syncthreads();
    int j = nt*256 + t;
    float acc = 0.f;
    for (int k = 0; k < 256; ++k) acc += xc[k] * w[(size_t)k*1024 + j];
    acc += bias[j];
    out[b*1024 + j] = acc > 0.f ? acc : 0.f;
}

__global__ __launch_bounds__(256) void k_fc2p(const float* __restrict__ hf1, const float* __restrict__ w,
                                              float* __restrict__ part){
    __shared__ float row[256];
    int b = blockIdx.x >> 2, ks = blockIdx.x & 3;
    int t = threadIdx.x;
    row[t] = hf1[b*1024 + ks*256 + t];
    __syncthreads();
    float acc = 0.f;
    const float* wc = w + (size_t)(ks*256)*256 + t;
    for (int k = 0; k < 256; ++k) acc += row[k] * wc[(size_t)k*256];
    part[((size_t)ks*NB + b)*256 + t] = acc;
}

__global__ __launch_bounds__(256) void k_fc2red(const float* __restrict__ part, const float* __restrict__ bias,
                                                const float* __restrict__ ow, const float* __restrict__ ob,
                                                float* __restrict__ out){
    __shared__ float s2[256];
    int b = blockIdx.x, t = threadIdx.x;
    float v = part[(size_t)b*256 + t] + part[((size_t)NB + b)*256 + t]
            + part[((size_t)2*NB + b)*256 + t] + part[((size_t)3*NB + b)*256 + t];
    v += bias[t];
    v = v > 0.f ? v : 0.f;
    s2[t] = v * ow[t];
    __syncthreads();
    if (t < 64){
        float a = s2[t] + s2[t + 64] + s2[t + 128] + s2[t + 192];
#pragma unroll
        for (int o = 32; o; o >>= 1) a += __shfl_xor(a, o);
        if (t == 0) out[b] = a + ob[0];
    }
}

extern "C" void kernel_launch(void* const* d_in, const int* in_sizes, int n_in,
                              void* d_out, int out_size, void* d_ws, size_t ws_size,
                              hipStream_t stream){
    const float* x    = (const float*)d_in[0];
    const int*  ei    = (const int*)d_in[1];
    const int*  batch = (const int*)d_in[2];
    const int*  target= (const int*)d_in[3];
    const float* W1   = (const float*)d_in[4];
    const float* as1w = (const float*)d_in[5];
    const float* ad1w = (const float*)d_in[6];
    const float* b1   = (const float*)d_in[7];
    const float* W2   = (const float*)d_in[8];
    const float* as2w = (const float*)d_in[9];
    const float* ad2w = (const float*)d_in[10];
    const float* b2   = (const float*)d_in[11];
    const float* fgw  = (const float*)d_in[12];
    const float* fgb  = (const float*)d_in[13];
    const float* emb  = (const float*)d_in[14];
    const float* cw   = (const float*)d_in[15];
    const float* cb   = (const float*)d_in[16];
    const float* fxw  = (const float*)d_in[17];
    const float* fxb  = (const float*)d_in[18];
    const float* f1w  = (const float*)d_in[19];
    const float* f1b  = (const float*)d_in[20];
    const float* f2w  = (const float*)d_in[21];
    const float* f2b  = (const float*)d_in[22];
    const float* ow   = (const float*)d_in[23];
    const float* ob   = (const float*)d_in[24];

    float* f = (float*)d_ws;
    size_t o = 0;
    float* aggf = f + o; o += (size_t)NN*D1;    // bf16 agg (lower half used)
    float* h1f = f + o; o += (size_t)NN*D1;     // bf16 h1 (half used); reused as Ag after gemm2m
    float* as1 = f + o; o += (size_t)NN*HEADS;
    float* ad1 = f + o; o += (size_t)NN*HEADS;
    float* xl2 = f + o; o += (size_t)NN*OD;
    float* h2  = f + o; o += (size_t)NN*OD;
    float* as2 = f + o; o += NN;
    float* ad2 = f + o; o += NN;
    float* gfc = f + o; o += NB*OD;
    float* hf1 = f + o; o += NB*1024;
    float* part= f + o; o += (size_t)4*NB*256;
    float* wt  = f + o; o += (size_t)PL*256;
    float* cbuf= f + o; o += (size_t)NB*3872;
    float* xtp = f + o; o += (size_t)16*NB*128;
    int* cnt   = (int*)(f + o); o += NN;
    int* off   = (int*)(f + o); o += NN + 1;
    int* csrc  = (int*)(f + o); o += ET;
    ushort* aggh = (ushort*)aggf;
    ushort* h1h  = (ushort*)h1f;
    float*  Ag   = h1f;    // h1h dead after gemm2m; abuild launches after
    (void)ws_size; (void)in_sizes; (void)n_in; (void)out_size;

    // CSR by destination
    hipMemsetAsync(cnt, 0, NN*sizeof(int), stream);
    k_hist<<<(ET + 255)/256, 256, 0, stream>>>(ei, cnt);
    k_scan<<<1, 1024, 0, stream>>>(cnt, off);
    hipMemsetAsync(cnt, 0, NN*sizeof(int), stream);
    k_fill<<<(ET + 255)/256, 256, 0, stream>>>(ei, off, cnt, csrc);

    // GAT layer 1 in x-space
    k_alpha1x<<<NN/64, 256, 0, stream>>>(x, W1, as1w, ad1w, as1, ad1);
    k_gat1x<<<NN, 64, 0, stream>>>(x, as1, ad1, off, csrc, aggh);
    k_post1<<<HEADS*256, 256, 0, stream>>>(aggh, W1, b1, h1h);

    // GAT layer 2: MFMA GEMM + fused alpha2 (B converted in-kernel)
    k_gemm2m<<<NN/64, 256, 0, stream>>>(h1h, W2, as2w, ad2w, xl2, as2, ad2);
    k_gat2<<<NN, 64, 0, stream>>>(xl2, as2, ad2, off, csrc, b2, h2);

    // pooling + graph fc (fused)
    k_poolfc<<<NB, 128, 0, stream>>>(h2, batch, fgw, fgb, gfc);

    // protein branch
    k_wt<<<1000, 256, 0, stream>>>(cw, wt);
    k_abuild<<<NB*4, 256, 0, stream>>>(target, wt, Ag);
    k_conv<<<NB*2, 256, 0, stream>>>(Ag, emb, cb, cbuf);
    k_xt<<<128, 256, 0, stream>>>(cbuf, fxw, xtp);

    // head (wide)
    k_fc1<<<NB*4, 256, 0, stream>>>(gfc, xtp, fxb, f1w, f1b, hf1);
    k_fc2p<<<NB*4, 256, 0, stream>>>(hf1, f2w, part);
    k_fc2red<<<NB, 256, 0, stream>>>(part, f2b, ow, ob, (float*)d_out);
}

// Round 19
// 365.017 us; speedup vs baseline: 1.1466x; 1.0926x over previous
//
#include <hip/hip_runtime.h>
#include <hip/hip_bf16.h>

using bf16 = __hip_bfloat16;

#define NN 16384
#define NE 262144
#define ET (NE + NN)
#define NB 128
#define FEAT 78
#define HEADS 10
#define D1 780
#define OD 128
#define PL 1000
#define VOC 26
#define SLOPE 0.2f

typedef __attribute__((ext_vector_type(8))) short short8;
typedef __attribute__((ext_vector_type(4))) float f32x4;

static __device__ __forceinline__ ushort f2bf(float f){
    bf16 h = __float2bfloat16(f);
    return *reinterpret_cast<ushort*>(&h);
}
static __device__ __forceinline__ float bf2f(ushort u){
    bf16 h;
    *reinterpret_cast<ushort*>(&h) = u;
    return __bfloat162float(h);
}

// ---------------- CSR build ----------------
__global__ void k_hist(const int* __restrict__ ei, int* __restrict__ cnt){
    int e = blockIdx.x*256 + threadIdx.x;
    if (e >= ET) return;
    int dst = (e < NE) ? ei[NE + e] : (e - NE);
    atomicAdd(&cnt[dst], 1);
}

// scan cnt -> off, and zero cnt in-place (reused as cursor by k_fill)
__global__ __launch_bounds__(1024) void k_scan(int* __restrict__ cnt, int* __restrict__ off){
    __shared__ int ps[1024];
    int t = threadIdx.x;
    int loc[16]; int s = 0;
#pragma unroll
    for (int j = 0; j < 16; ++j){ loc[j] = cnt[t*16 + j]; s += loc[j]; }
#pragma unroll
    for (int j = 0; j < 16; ++j) cnt[t*16 + j] = 0;
    ps[t] = s; __syncthreads();
    for (int d = 1; d < 1024; d <<= 1){
        int v = (t >= d) ? ps[t - d] : 0;
        __syncthreads();
        ps[t] += v;
        __syncthreads();
    }
    int run = (t == 0) ? 0 : ps[t - 1];
#pragma unroll
    for (int j = 0; j < 16; ++j){ off[t*16 + j] = run; run += loc[j]; }
    if (t == 1023) off[NN] = run;
}

__global__ void k_fill(const int* __restrict__ ei, const int* __restrict__ off,
                       int* __restrict__ cur, int* __restrict__ csrc){
    int e = blockIdx.x*256 + threadIdx.x;
    if (e >= ET) return;
    int src, dst;
    if (e < NE){ src = ei[e]; dst = ei[NE + e]; } else { src = e - NE; dst = src; }
    int p = off[dst] + atomicAdd(&cur[dst], 1);
    csrc[p] = src;
}

// ---------------- GAT layer 1 (x-space) ----------------
__global__ __launch_bounds__(256) void k_alpha1x(const float* __restrict__ x, const float* __restrict__ W1,
                                                 const float* __restrict__ asw, const float* __restrict__ adw,
                                                 float* __restrict__ as1, float* __restrict__ ad1){
    __shared__ float xs[64*79];
    __shared__ float va[D1], vd[D1];
    int n0 = blockIdx.x * 64, t = threadIdx.x;
    for (int i = t; i < 64*FEAT; i += 256){
        int n = i / FEAT, k = i % FEAT;
        xs[n*79 + k] = x[(size_t)n0*FEAT + i];
    }
    for (int idx = t; idx < D1; idx += 256){
        int h = idx / FEAT, k = idx % FEAT;
        const float* wr = W1 + (size_t)k*D1 + h*FEAT;
        const float* pa = asw + h*FEAT;
        const float* pd = adw + h*FEAT;
        float a = 0.f, d = 0.f;
        for (int j = 0; j < FEAT; ++j){ float w = wr[j]; a += w*pa[j]; d += w*pd[j]; }
        va[idx] = a; vd[idx] = d;
    }
    __syncthreads();
    for (int p = t; p < 64*HEADS; p += 256){
        int h = p >> 6, nl = p & 63;
        const float* xr = xs + nl*79;
        const float* pa = va + h*FEAT; const float* pd = vd + h*FEAT;
        float a = 0.f, d = 0.f;
        for (int k = 0; k < FEAT; ++k){ float xv = xr[k]; a += xv*pa[k]; d += xv*pd[k]; }
        as1[(size_t)(n0 + nl)*HEADS + h] = a;
        ad1[(size_t)(n0 + nl)*HEADS + h] = d;
    }
}

// per dst (64-thread block): lane-owned alpha; chunk-register staged f32 gather; bf16 agg out
__global__ __launch_bounds__(64) void k_gat1x(const float* __restrict__ x, const float* __restrict__ as1,
                                              const float* __restrict__ ad1, const int* __restrict__ off,
                                              const int* __restrict__ csrc,
                                              ushort* __restrict__ aggh){
    int dst = blockIdx.x, lane = threadIdx.x;
    int beg = off[dst], end = off[dst + 1];
    int deg = end - beg;
    float adh[HEADS];
#pragma unroll
    for (int h = 0; h < HEADS; ++h) adh[h] = ad1[(size_t)dst*HEADS + h];
    int s0 = 0;
    float p[HEADS], mx[HEADS];
#pragma unroll
    for (int h = 0; h < HEADS; ++h){ mx[h] = -1e30f; p[h] = 0.f; }
    if (lane < deg){
        s0 = csrc[beg + lane];
#pragma unroll
        for (int h = 0; h < HEADS; ++h){
            float v = as1[(size_t)s0*HEADS + h] + adh[h];
            v = v > 0.f ? v : SLOPE*v;
            p[h] = v; mx[h] = v;
        }
    }
    if (deg > 64){
        for (int e = beg + 64 + lane; e < end; e += 64){
            int s = csrc[e];
#pragma unroll
            for (int h = 0; h < HEADS; ++h){
                float v = as1[(size_t)s*HEADS + h] + adh[h];
                v = v > 0.f ? v : SLOPE*v;
                mx[h] = fmaxf(mx[h], v);
            }
        }
    }
#pragma unroll
    for (int h = 0; h < HEADS; ++h)
        for (int o = 32; o; o >>= 1) mx[h] = fmaxf(mx[h], __shfl_xor(mx[h], o));
    float sm[HEADS];
#pragma unroll
    for (int h = 0; h < HEADS; ++h) sm[h] = 0.f;
    if (lane < deg){
#pragma unroll
        for (int h = 0; h < HEADS; ++h){ p[h] = __expf(p[h] - mx[h]); sm[h] = p[h]; }
    }
    if (deg > 64){
        for (int e = beg + 64 + lane; e < end; e += 64){
            int s = csrc[e];
#pragma unroll
            for (int h = 0; h < HEADS; ++h){
                float v = as1[(size_t)s*HEADS + h] + adh[h];
                v = v > 0.f ? v : SLOPE*v;
                sm[h] += __expf(v - mx[h]);
            }
        }
    }
    float inv[HEADS];
#pragma unroll
    for (int h = 0; h < HEADS; ++h){
        for (int o = 32; o; o >>= 1) sm[h] += __shfl_xor(sm[h], o);
        inv[h] = 1.f/(sm[h] + 1e-16f);
        p[h] = (lane < deg) ? p[h]*inv[h] : 0.f;
    }
    float acc1[HEADS], acc2[HEADS];
#pragma unroll
    for (int h = 0; h < HEADS; ++h){ acc1[h] = 0.f; acc2[h] = 0.f; }
    int cnt0 = deg < 64 ? deg : 64;
    for (int c0 = 0; c0 < cnt0; c0 += 16){
        float r1[16], r2[16];
#pragma unroll
        for (int i = 0; i < 16; ++i){
            int s = __shfl(s0, c0 + i);
            const float* xr = x + (size_t)s*FEAT;
            r1[i] = xr[lane];
            r2[i] = (lane < FEAT - 64) ? xr[64 + lane] : 0.f;
        }
#pragma unroll
        for (int i = 0; i < 16; ++i){
            if (c0 + i < cnt0){
#pragma unroll
                for (int h = 0; h < HEADS; ++h){
                    float al = __shfl(p[h], c0 + i);
                    acc1[h] += al*r1[i];
                    acc2[h] += al*r2[i];
                }
            }
        }
    }
    if (deg > 64){
        for (int base = beg + 64; base < end; base += 64){
            int cnt = min(64, end - base);
            int s1 = 0;
            float pp[HEADS];
#pragma unroll
            for (int h = 0; h < HEADS; ++h) pp[h] = 0.f;
            if (lane < cnt){
                s1 = csrc[base + lane];
#pragma unroll
                for (int h = 0; h < HEADS; ++h){
                    float v = as1[(size_t)s1*HEADS + h] + adh[h];
                    v = v > 0.f ? v : SLOPE*v;
                    pp[h] = __expf(v - mx[h])*inv[h];
                }
            }
            for (int c0 = 0; c0 < cnt; c0 += 16){
                float r1[16], r2[16];
#pragma unroll
                for (int i = 0; i < 16; ++i){
                    int s = __shfl(s1, c0 + i);
                    const float* xr = x + (size_t)s*FEAT;
                    r1[i] = xr[lane];
                    r2[i] = (lane < FEAT - 64) ? xr[64 + lane] : 0.f;
                }
#pragma unroll
                for (int i = 0; i < 16; ++i){
                    if (c0 + i < cnt){
#pragma unroll
                        for (int h = 0; h < HEADS; ++h){
                            float al = __shfl(pp[h], c0 + i);
                            acc1[h] += al*r1[i];
                            acc2[h] += al*r2[i];
                        }
                    }
                }
            }
        }
    }
#pragma unroll
    for (int h = 0; h < HEADS; ++h)
        aggh[(size_t)dst*D1 + h*FEAT + lane] = f2bf(acc1[h]);
    if (lane < FEAT - 64){
#pragma unroll
        for (int h = 0; h < HEADS; ++h)
            aggh[(size_t)dst*D1 + h*FEAT + 64 + lane] = f2bf(acc2[h]);
    }
}

// block = (head, node-tile-64): bf16 agg in, bf16 h1 out
__global__ __launch_bounds__(256) void k_post1(const ushort* __restrict__ aggh, const float* __restrict__ W1,
                                               const float* __restrict__ b1, ushort* __restrict__ h1h){
    __shared__ float w1s[FEAT][80];
    __shared__ float ags[64][81];
    __shared__ float bsh[FEAT];
    int ht = blockIdx.x >> 8;
    int nt = blockIdx.x & 255;
    int n0 = nt * 64;
    int t = threadIdx.x;
    for (int i = t; i < FEAT*FEAT; i += 256){
        int k = i / FEAT, j = i % FEAT;
        w1s[k][j] = W1[(size_t)k*D1 + ht*FEAT + j];
    }
    for (int i = t; i < 64*FEAT; i += 256){
        int r = i / FEAT, k = i % FEAT;
        ags[r][k] = bf2f(aggh[(size_t)(n0 + r)*D1 + ht*FEAT + k]);
    }
    if (t < FEAT) bsh[t] = b1[ht*FEAT + t];
    __syncthreads();
    if (t < 208){
        int rg = t / 13, cg = t % 13;
        int c0 = cg*6;
        float acc[4][6];
#pragma unroll
        for (int i = 0; i < 4; ++i)
#pragma unroll
            for (int j = 0; j < 6; ++j) acc[i][j] = 0.f;
        for (int k = 0; k < FEAT; ++k){
            float av[4];
#pragma unroll
            for (int i = 0; i < 4; ++i) av[i] = ags[rg*4 + i][k];
            float2 w01 = *(const float2*)&w1s[k][c0];
            float2 w23 = *(const float2*)&w1s[k][c0 + 2];
            float2 w45 = *(const float2*)&w1s[k][c0 + 4];
            float wv[6] = {w01.x, w01.y, w23.x, w23.y, w45.x, w45.y};
#pragma unroll
            for (int i = 0; i < 4; ++i)
#pragma unroll
                for (int j = 0; j < 6; ++j) acc[i][j] += av[i]*wv[j];
        }
#pragma unroll
        for (int i = 0; i < 4; ++i){
#pragma unroll
            for (int j = 0; j < 6; ++j){
                float v = acc[i][j] + bsh[c0 + j];
                v = v > 0.f ? v : __expf(v) - 1.f;   // ELU
                h1h[(size_t)(n0 + rg*4 + i)*D1 + ht*FEAT + c0 + j] = f2bf(v);
            }
        }
    }
}

// ---------------- GAT layer 2 GEMM via MFMA, fused alpha2 ----------------
__global__ __launch_bounds__(256) void k_gemm2m(const ushort* __restrict__ h1h, const float* __restrict__ w2,
                                                const float* __restrict__ s2w, const float* __restrict__ d2w,
                                                float* __restrict__ xl2,
                                                float* __restrict__ as2, float* __restrict__ ad2){
    __shared__ ushort As[64][40];
    __shared__ ushort Bs[128][40];
    int r0 = blockIdx.x * 64;
    int t = threadIdx.x;
    int w = t >> 6, l = t & 63;
    f32x4 acc[8];
#pragma unroll
    for (int i = 0; i < 8; ++i) acc[i] = (f32x4){0.f, 0.f, 0.f, 0.f};
    for (int k0 = 0; k0 < D1; k0 += 32){
        {
            int r = t >> 2, kq = (t & 3)*8;
            int gk = k0 + kq;
            ushort tmp[8];
            if (gk + 8 <= D1){
                *(ushort4*)&tmp[0] = *(const ushort4*)&h1h[(size_t)(r0 + r)*D1 + gk];
                *(ushort4*)&tmp[4] = *(const ushort4*)&h1h[(size_t)(r0 + r)*D1 + gk + 4];
            } else {
#pragma unroll
                for (int j = 0; j < 8; ++j)
                    tmp[j] = (gk + j < D1) ? h1h[(size_t)(r0 + r)*D1 + gk + j] : (ushort)0;
            }
            *(ushort4*)&As[r][kq]     = *(ushort4*)&tmp[0];
            *(ushort4*)&As[r][kq + 4] = *(ushort4*)&tmp[4];
        }
        {
            int n8 = (t & 15)*8, kk = t >> 4;
#pragma unroll
            for (int half = 0; half < 2; ++half){
                int k = kk + half*16;
                ushort tmp[8];
                if (k0 + k < D1){
                    float4 f0 = *(const float4*)&w2[(size_t)(k0 + k)*OD + n8];
                    float4 f1 = *(const float4*)&w2[(size_t)(k0 + k)*OD + n8 + 4];
                    tmp[0] = f2bf(f0.x); tmp[1] = f2bf(f0.y); tmp[2] = f2bf(f0.z); tmp[3] = f2bf(f0.w);
                    tmp[4] = f2bf(f1.x); tmp[5] = f2bf(f1.y); tmp[6] = f2bf(f1.z); tmp[7] = f2bf(f1.w);
                } else {
#pragma unroll
                    for (int j = 0; j < 8; ++j) tmp[j] = 0;
                }
#pragma unroll
                for (int j = 0; j < 8; ++j) Bs[n8 + j][k] = tmp[j];
            }
        }
        __syncthreads();
        short8 a = *(const short8*)&As[w*16 + (l & 15)][(l >> 4)*8];
#pragma unroll
        for (int nt = 0; nt < 8; ++nt){
            short8 b = *(const short8*)&Bs[nt*16 + (l & 15)][(l >> 4)*8];
            acc[nt] = __builtin_amdgcn_mfma_f32_16x16x32_bf16(a, b, acc[nt], 0, 0, 0);
        }
        __syncthreads();
    }
    int colg = l & 15, kg = l >> 4;
    float sa[4] = {0.f,0.f,0.f,0.f}, sd[4] = {0.f,0.f,0.f,0.f};
#pragma unroll
    for (int nt = 0; nt < 8; ++nt){
        int c = nt*16 + colg;
        float wsv = s2w[c], wdv = d2w[c];
#pragma unroll
        for (int r = 0; r < 4; ++r){
            float v = acc[nt][r];
            int row = r0 + w*16 + kg*4 + r;
            xl2[(size_t)row*OD + c] = v;
            sa[r] += v*wsv; sd[r] += v*wdv;
        }
    }
#pragma unroll
    for (int r = 0; r < 4; ++r){
#pragma unroll
        for (int o = 8; o; o >>= 1){ sa[r] += __shfl_xor(sa[r], o); sd[r] += __shfl_xor(sd[r], o); }
    }
    if (colg == 0){
        int row = r0 + w*16 + kg*4;
#pragma unroll
        for (int r = 0; r < 4; ++r){ as2[row + r] = sa[r]; ad2[row + r] = sd[r]; }
    }
}

// per dst (64-thread block): lane-owned alpha, chunk-staged f32 gather
__global__ __launch_bounds__(64) void k_gat2(const float* __restrict__ xl2, const float* __restrict__ as2,
                                             const float* __restrict__ ad2, const int* __restrict__ off,
                                             const int* __restrict__ csrc, const float* __restrict__ b2,
                                             float* __restrict__ h2){
    int dst = blockIdx.x, lane = threadIdx.x;
    int beg = off[dst], end = off[dst + 1];
    int deg = end - beg;
    float ad = ad2[dst];
    int s0 = 0; float v0 = -1e30f;
    if (lane < deg){
        s0 = csrc[beg + lane];
        float v = as2[s0] + ad;
        v0 = v > 0.f ? v : SLOPE*v;
    }
    float m = v0;
    if (deg > 64){
        for (int e = beg + 64 + lane; e < end; e += 64){
            float v = as2[csrc[e]] + ad; v = v > 0.f ? v : SLOPE*v;
            m = fmaxf(m, v);
        }
    }
    for (int o = 32; o; o >>= 1) m = fmaxf(m, __shfl_xor(m, o));
    float pe = (lane < deg) ? __expf(v0 - m) : 0.f;
    float sm = pe;
    if (deg > 64){
        for (int e = beg + 64 + lane; e < end; e += 64){
            float v = as2[csrc[e]] + ad; v = v > 0.f ? v : SLOPE*v;
            sm += __expf(v - m);
        }
    }
    for (int o = 32; o; o >>= 1) sm += __shfl_xor(sm, o);
    float inv = 1.f / (sm + 1e-16f);
    float p = pe * inv;
    float a0 = 0.f, a1 = 0.f;
    int cnt0 = deg < 64 ? deg : 64;
    for (int c0 = 0; c0 < cnt0; c0 += 16){
        float r1[16], r2[16];
#pragma unroll
        for (int i = 0; i < 16; ++i){
            int s = __shfl(s0, c0 + i);
            r1[i] = xl2[(size_t)s*OD + lane];
            r2[i] = xl2[(size_t)s*OD + 64 + lane];
        }
#pragma unroll
        for (int i = 0; i < 16; ++i){
            if (c0 + i < cnt0){
                float al = __shfl(p, c0 + i);
                a0 += al*r1[i];
                a1 += al*r2[i];
            }
        }
    }
    if (deg > 64){
        for (int base = beg + 64; base < end; base += 64){
            int cnt = min(64, end - base);
            int s1 = 0; float pp = 0.f;
            if (lane < cnt){
                s1 = csrc[base + lane];
                float v = as2[s1] + ad; v = v > 0.f ? v : SLOPE*v;
                pp = __expf(v - m) * inv;
            }
            for (int c0 = 0; c0 < cnt; c0 += 16){
                float r1[16], r2[16];
#pragma unroll
                for (int i = 0; i < 16; ++i){
                    int s = __shfl(s1, c0 + i);
                    r1[i] = xl2[(size_t)s*OD + lane];
                    r2[i] = xl2[(size_t)s*OD + 64 + lane];
                }
#pragma unroll
                for (int i = 0; i < 16; ++i){
                    if (c0 + i < cnt){
                        float al = __shfl(pp, c0 + i);
                        a0 += al*r1[i];
                        a1 += al*r2[i];
                    }
                }
            }
        }
    }
    float o0 = a0 + b2[lane];      o0 = o0 > 0.f ? o0 : 0.f;
    float o1 = a1 + b2[64 + lane]; o1 = o1 > 0.f ? o1 : 0.f;
    h2[(size_t)dst*OD + lane] = o0;
    h2[(size_t)dst*OD + 64 + lane] = o1;
}

// ---------------- protein branch ----------------
// A-partials per (b, seg): direct convw reads (transposed indexing), integer LDS atomics
__global__ __launch_bounds__(256) void k_abuild(const int* __restrict__ target, const float* __restrict__ convw,
                                                float* __restrict__ Ag){
    __shared__ int Ai[VOC][256];
    __shared__ int tss[256];
    int b = blockIdx.x >> 2, seg = blockIdx.x & 3;
    int t = threadIdx.x;
#pragma unroll
    for (int v = 0; v < VOC; ++v) Ai[v][t] = 0;
    if (t < 250) tss[t] = target[b*PL + seg*250 + t];
    __syncthreads();
    // wt[i][t] == convw[(t>>3)*PL*8 + i*8 + (t&7)]; i = seg*250 + ii
    const float* wp = convw + (size_t)(t >> 3)*(PL*8) + (size_t)(seg*250)*8 + (t & 7);
    const float SC = 16777216.0f;               // 2^24
    for (int i = 0; i < 250; ++i){
        float w = wp[(size_t)i*8];
        int q = __float2int_rn(w * SC);
        atomicAdd(&Ai[tss[i]][t], q);           // native ds_add_u32
    }
    __syncthreads();
    const float INV = 5.9604644775390625e-08f;  // 2^-24
    float* Ao = Ag + (size_t)blockIdx.x*VOC*256 + t;
#pragma unroll
    for (int v = 0; v < VOC; ++v) Ao[(size_t)v*256] = (float)Ai[v][t] * INV;
}

__global__ __launch_bounds__(256) void k_conv(const float* __restrict__ Ag, const float* __restrict__ emb,
                                              const float* __restrict__ convb, float* __restrict__ cbuf){
    __shared__ float As[VOC][128];
    __shared__ float embs[VOC*128 + 16];
    int b = blockIdx.x >> 1, half = blockIdx.x & 1;
    int t = threadIdx.x;
    for (int i = t; i < VOC*128; i += 256){
        int v = i >> 7, c = i & 127;
        float s = 0.f;
#pragma unroll
        for (int seg = 0; seg < 4; ++seg)
            s += Ag[((size_t)(b*4 + seg)*VOC + v)*256 + half*128 + c];
        As[v][c] = s;
        embs[i] = emb[i];
    }
    if (t < 16) embs[VOC*128 + t] = 0.f;
    __syncthreads();
    int o_l = t >> 4, pg = t & 15, p0 = pg * 8;
    float accp[8];
#pragma unroll
    for (int i = 0; i < 8; ++i) accp[i] = 0.f;
    for (int v = 0; v < VOC; ++v){
        float w[15];
        const float* er = embs + v*128 + p0;
#pragma unroll
        for (int i = 0; i < 15; ++i) w[i] = er[i];
#pragma unroll
        for (int k2 = 0; k2 < 8; ++k2){
            float a = As[v][o_l*8 + k2];
#pragma unroll
            for (int j = 0; j < 8; ++j) accp[j] += a * w[j + k2];
        }
    }
    float cbv = convb[half*16 + o_l];
#pragma unroll
    for (int j = 0; j < 8; ++j){
        int p = p0 + j;
        if (p < 121){
            float v2 = accp[j] + cbv;
            cbuf[(size_t)b*3872 + (half*16 + o_l)*121 + p] = v2 > 0.f ? v2 : 0.f;
        }
    }
}

__global__ __launch_bounds__(256) void k_xt(const float* __restrict__ cbuf, const float* __restrict__ fxw,
                                            float* __restrict__ xtp){
    __shared__ float csh[16][242];
    int kt = blockIdx.x >> 3, bt = blockIdx.x & 7;
    int t = threadIdx.x;
    for (int i = t; i < 16*242; i += 256){
        int bb = i / 242, kk = i % 242;
        csh[bb][kk] = cbuf[(size_t)(bt*16 + bb)*3872 + kt*242 + kk];
    }
    __syncthreads();
    int j = t & 127, bh = t >> 7;
    float acc[8];
#pragma unroll
    for (int i = 0; i < 8; ++i) acc[i] = 0.f;
    for (int kk = 0; kk < 242; ++kk){
        float w = fxw[(size_t)(kt*242 + kk)*128 + j];
#pragma unroll
        for (int bb = 0; bb < 8; ++bb) acc[bb] += csh[bh*8 + bb][kk] * w;
    }
#pragma unroll
    for (int bb = 0; bb < 8; ++bb)
        xtp[(size_t)kt*NB*128 + (size_t)(bt*16 + bh*8 + bb)*128 + j] = acc[bb];
}

// ---------------- head: fc1 with fused pool+fcg (512 blocks), fc2 partials, reduce+out ----------------
__global__ __launch_bounds__(256) void k_fc1(const float* __restrict__ h2, const int* __restrict__ batch,
                                             const float* __restrict__ fgw, const float* __restrict__ fgb,
                                             const float* __restrict__ xtp, const float* __restrict__ fxb,
                                             const float* __restrict__ w, const float* __restrict__ bias,
                                             float* __restrict__ out){
    __shared__ float row[OD];
    __shared__ float xc[256];
    int b = blockIdx.x >> 2, nt = blockIdx.x & 3;
    int t = threadIdx.x;
    int lo = 0, hi = NN;
    while (lo < hi){ int mid = (lo + hi) >> 1; if (batch[mid] < b) lo = mid + 1; else hi = mid; }
    int s0 = lo;
    lo = s0; hi = NN;
    while (lo < hi){ int mid = (lo + hi) >> 1; if (batch[mid] < b + 1) lo = mid + 1; else hi = mid; }
    int s1 = lo;
    if (t < 128){
        float mx = 0.f;
        for (int n = s0; n < s1; ++n) mx = fmaxf(mx, h2[(size_t)n*OD + t]);
        row[t] = mx;
    } else {
        int j = t - 128;
        float s = fxb[j];
#pragma unroll
        for (int kt = 0; kt < 16; ++kt) s += xtp[(size_t)kt*NB*128 + (size_t)b*128 + j];
        xc[t] = s;
    }
    __syncthreads();
    if (t < 128){
        float acc = 0.f;
        for (int k = 0; k < OD; ++k) acc += row[k] * fgw[k*OD + t];
        acc += fgb[t];
        xc[t] = acc > 0.f ? acc : 0.f;
    }
    __syncthreads();
    int j = nt*256 + t;
    float acc = 0.f;
    for (int k = 0; k < 256; ++k) acc += xc[k] * w[(size_t)k*1024 + j];
    acc += bias[j];
    out[b*1024 + j] = acc > 0.f ? acc : 0.f;
}

__global__ __launch_bounds__(256) void k_fc2p(const float* __restrict__ hf1, const float* __restrict__ w,
                                              float* __restrict__ part){
    __shared__ float row[256];
    int b = blockIdx.x >> 2, ks = blockIdx.x & 3;
    int t = threadIdx.x;
    row[t] = hf1[b*1024 + ks*256 + t];
    __syncthreads();
    float acc = 0.f;
    const float* wc = w + (size_t)(ks*256)*256 + t;
    for (int k = 0; k < 256; ++k) acc += row[k] * wc[(size_t)k*256];
    part[((size_t)ks*NB + b)*256 + t] = acc;
}

__global__ __launch_bounds__(256) void k_fc2red(const float* __restrict__ part, const float* __restrict__ bias,
                                                const float* __restrict__ ow, const float* __restrict__ ob,
                                                float* __restrict__ out){
    __shared__ float s2[256];
    int b = blockIdx.x, t = threadIdx.x;
    float v = part[(size_t)b*256 + t] + part[((size_t)NB + b)*256 + t]
            + part[((size_t)2*NB + b)*256 + t] + part[((size_t)3*NB + b)*256 + t];
    v += bias[t];
    v = v > 0.f ? v : 0.f;
    s2[t] = v * ow[t];
    __syncthreads();
    if (t < 64){
        float a = s2[t] + s2[t + 64] + s2[t + 128] + s2[t + 192];
#pragma unroll
        for (int o = 32; o; o >>= 1) a += __shfl_xor(a, o);
        if (t == 0) out[b] = a + ob[0];
    }
}

extern "C" void kernel_launch(void* const* d_in, const int* in_sizes, int n_in,
                              void* d_out, int out_size, void* d_ws, size_t ws_size,
                              hipStream_t stream){
    const float* x    = (const float*)d_in[0];
    const int*  ei    = (const int*)d_in[1];
    const int*  batch = (const int*)d_in[2];
    const int*  target= (const int*)d_in[3];
    const float* W1   = (const float*)d_in[4];
    const float* as1w = (const float*)d_in[5];
    const float* ad1w = (const float*)d_in[6];
    const float* b1   = (const float*)d_in[7];
    const float* W2   = (const float*)d_in[8];
    const float* as2w = (const float*)d_in[9];
    const float* ad2w = (const float*)d_in[10];
    const float* b2   = (const float*)d_in[11];
    const float* fgw  = (const float*)d_in[12];
    const float* fgb  = (const float*)d_in[13];
    const float* emb  = (const float*)d_in[14];
    const float* cw   = (const float*)d_in[15];
    const float* cb   = (const float*)d_in[16];
    const float* fxw  = (const float*)d_in[17];
    const float* fxb  = (const float*)d_in[18];
    const float* f1w  = (const float*)d_in[19];
    const float* f1b  = (const float*)d_in[20];
    const float* f2w  = (const float*)d_in[21];
    const float* f2b  = (const float*)d_in[22];
    const float* ow   = (const float*)d_in[23];
    const float* ob   = (const float*)d_in[24];

    float* f = (float*)d_ws;
    size_t o = 0;
    float* aggf = f + o; o += (size_t)NN*D1;    // bf16 agg (lower half used)
    float* h1f = f + o; o += (size_t)NN*D1;     // bf16 h1 (half used); reused as Ag after gemm2m
    float* as1 = f + o; o += (size_t)NN*HEADS;
    float* ad1 = f + o; o += (size_t)NN*HEADS;
    float* xl2 = f + o; o += (size_t)NN*OD;
    float* h2  = f + o; o += (size_t)NN*OD;
    float* as2 = f + o; o += NN;
    float* ad2 = f + o; o += NN;
    float* hf1 = f + o; o += NB*1024;
    float* part= f + o; o += (size_t)4*NB*256;
    float* cbuf= f + o; o += (size_t)NB*3872;
    float* xtp = f + o; o += (size_t)16*NB*128;
    int* cnt   = (int*)(f + o); o += NN;
    int* off   = (int*)(f + o); o += NN + 1;
    int* csrc  = (int*)(f + o); o += ET;
    ushort* aggh = (ushort*)aggf;
    ushort* h1h  = (ushort*)h1f;
    float*  Ag   = h1f;    // h1h dead after gemm2m; abuild launches after
    (void)ws_size; (void)in_sizes; (void)n_in; (void)out_size;

    // CSR by destination (k_scan zeroes cnt for reuse as cursor)
    hipMemsetAsync(cnt, 0, NN*sizeof(int), stream);
    k_hist<<<(ET + 255)/256, 256, 0, stream>>>(ei, cnt);
    k_scan<<<1, 1024, 0, stream>>>(cnt, off);
    k_fill<<<(ET + 255)/256, 256, 0, stream>>>(ei, off, cnt, csrc);

    // GAT layer 1 in x-space
    k_alpha1x<<<NN/64, 256, 0, stream>>>(x, W1, as1w, ad1w, as1, ad1);
    k_gat1x<<<NN, 64, 0, stream>>>(x, as1, ad1, off, csrc, aggh);
    k_post1<<<HEADS*256, 256, 0, stream>>>(aggh, W1, b1, h1h);

    // GAT layer 2: MFMA GEMM + fused alpha2
    k_gemm2m<<<NN/64, 256, 0, stream>>>(h1h, W2, as2w, ad2w, xl2, as2, ad2);
    k_gat2<<<NN, 64, 0, stream>>>(xl2, as2, ad2, off, csrc, b2, h2);

    // protein branch (k_wt deleted: abuild reads convw directly)
    k_abuild<<<NB*4, 256, 0, stream>>>(target, cw, Ag);
    k_conv<<<NB*2, 256, 0, stream>>>(Ag, emb, cb, cbuf);
    k_xt<<<128, 256, 0, stream>>>(cbuf, fxw, xtp);

    // head (pool+fcg fused into fc1)
    k_fc1<<<NB*4, 256, 0, stream>>>(h2, batch, fgw, fgb, xtp, fxb, f1w, f1b, hf1);
    k_fc2p<<<NB*4, 256, 0, stream>>>(hf1, f2w, part);
    k_fc2red<<<NB, 256, 0, stream>>>(part, f2b, ow, ob, (float*)d_out);
}

// Round 20
// 360.088 us; speedup vs baseline: 1.1623x; 1.0137x over previous
//
#include <hip/hip_runtime.h>
#include <hip/hip_bf16.h>

using bf16 = __hip_bfloat16;

#define NN 16384
#define NE 262144
#define ET (NE + NN)
#define NB 128
#define FEAT 78
#define HEADS 10
#define D1 780
#define OD 128
#define PL 1000
#define VOC 26
#define SLOPE 0.2f

typedef __attribute__((ext_vector_type(8))) short short8;
typedef __attribute__((ext_vector_type(4))) float f32x4;

static __device__ __forceinline__ ushort f2bf(float f){
    bf16 h = __float2bfloat16(f);
    return *reinterpret_cast<ushort*>(&h);
}
static __device__ __forceinline__ float bf2f(ushort u){
    bf16 h;
    *reinterpret_cast<ushort*>(&h) = u;
    return __bfloat162float(h);
}

// ---------------- GAT layer 1 alpha (runs FIRST; blocks 0..15 also zero cnt) ----------------
__global__ __launch_bounds__(256) void k_alpha1x(const float* __restrict__ x, const float* __restrict__ W1,
                                                 const float* __restrict__ asw, const float* __restrict__ adw,
                                                 float* __restrict__ as1, float* __restrict__ ad1,
                                                 int* __restrict__ cnt){
    __shared__ float xs[64*79];
    __shared__ float va[D1], vd[D1];
    int n0 = blockIdx.x * 64, t = threadIdx.x;
    if (blockIdx.x < 16){
        ((int4*)cnt)[blockIdx.x*256 + t] = make_int4(0,0,0,0);   // 16*256*4 = NN ints
    }
    for (int i = t; i < 64*FEAT; i += 256){
        int n = i / FEAT, k = i % FEAT;
        xs[n*79 + k] = x[(size_t)n0*FEAT + i];
    }
    for (int idx = t; idx < D1; idx += 256){
        int h = idx / FEAT, k = idx % FEAT;
        const float* wr = W1 + (size_t)k*D1 + h*FEAT;
        const float* pa = asw + h*FEAT;
        const float* pd = adw + h*FEAT;
        float a = 0.f, d = 0.f;
        for (int j = 0; j < FEAT; ++j){ float w = wr[j]; a += w*pa[j]; d += w*pd[j]; }
        va[idx] = a; vd[idx] = d;
    }
    __syncthreads();
    for (int p = t; p < 64*HEADS; p += 256){
        int h = p >> 6, nl = p & 63;
        const float* xr = xs + nl*79;
        const float* pa = va + h*FEAT; const float* pd = vd + h*FEAT;
        float a = 0.f, d = 0.f;
        for (int k = 0; k < FEAT; ++k){ float xv = xr[k]; a += xv*pa[k]; d += xv*pd[k]; }
        as1[(size_t)(n0 + nl)*HEADS + h] = a;
        ad1[(size_t)(n0 + nl)*HEADS + h] = d;
    }
}

// ---------------- CSR build ----------------
__global__ void k_hist(const int* __restrict__ ei, int* __restrict__ cnt){
    int e = blockIdx.x*256 + threadIdx.x;
    if (e >= ET) return;
    int dst = (e < NE) ? ei[NE + e] : (e - NE);
    atomicAdd(&cnt[dst], 1);
}

// scan cnt -> off, and zero cnt in-place (reused as cursor by k_fill)
__global__ __launch_bounds__(1024) void k_scan(int* __restrict__ cnt, int* __restrict__ off){
    __shared__ int ps[1024];
    int t = threadIdx.x;
    int loc[16]; int s = 0;
#pragma unroll
    for (int j = 0; j < 16; ++j){ loc[j] = cnt[t*16 + j]; s += loc[j]; }
#pragma unroll
    for (int j = 0; j < 16; ++j) cnt[t*16 + j] = 0;
    ps[t] = s; __syncthreads();
    for (int d = 1; d < 1024; d <<= 1){
        int v = (t >= d) ? ps[t - d] : 0;
        __syncthreads();
        ps[t] += v;
        __syncthreads();
    }
    int run = (t == 0) ? 0 : ps[t - 1];
#pragma unroll
    for (int j = 0; j < 16; ++j){ off[t*16 + j] = run; run += loc[j]; }
    if (t == 1023) off[NN] = run;
}

__global__ void k_fill(const int* __restrict__ ei, const int* __restrict__ off,
                       int* __restrict__ cur, int* __restrict__ csrc){
    int e = blockIdx.x*256 + threadIdx.x;
    if (e >= ET) return;
    int src, dst;
    if (e < NE){ src = ei[e]; dst = ei[NE + e]; } else { src = e - NE; dst = src; }
    int p = off[dst] + atomicAdd(&cur[dst], 1);
    csrc[p] = src;
}

// per dst (64-thread block): lane-owned alpha; chunk-register staged f32 gather; bf16 agg out
__global__ __launch_bounds__(64) void k_gat1x(const float* __restrict__ x, const float* __restrict__ as1,
                                              const float* __restrict__ ad1, const int* __restrict__ off,
                                              const int* __restrict__ csrc,
                                              ushort* __restrict__ aggh){
    int dst = blockIdx.x, lane = threadIdx.x;
    int beg = off[dst], end = off[dst + 1];
    int deg = end - beg;
    float adh[HEADS];
#pragma unroll
    for (int h = 0; h < HEADS; ++h) adh[h] = ad1[(size_t)dst*HEADS + h];
    int s0 = 0;
    float p[HEADS], mx[HEADS];
#pragma unroll
    for (int h = 0; h < HEADS; ++h){ mx[h] = -1e30f; p[h] = 0.f; }
    if (lane < deg){
        s0 = csrc[beg + lane];
#pragma unroll
        for (int h = 0; h < HEADS; ++h){
            float v = as1[(size_t)s0*HEADS + h] + adh[h];
            v = v > 0.f ? v : SLOPE*v;
            p[h] = v; mx[h] = v;
        }
    }
    if (deg > 64){
        for (int e = beg + 64 + lane; e < end; e += 64){
            int s = csrc[e];
#pragma unroll
            for (int h = 0; h < HEADS; ++h){
                float v = as1[(size_t)s*HEADS + h] + adh[h];
                v = v > 0.f ? v : SLOPE*v;
                mx[h] = fmaxf(mx[h], v);
            }
        }
    }
#pragma unroll
    for (int h = 0; h < HEADS; ++h)
        for (int o = 32; o; o >>= 1) mx[h] = fmaxf(mx[h], __shfl_xor(mx[h], o));
    float sm[HEADS];
#pragma unroll
    for (int h = 0; h < HEADS; ++h) sm[h] = 0.f;
    if (lane < deg){
#pragma unroll
        for (int h = 0; h < HEADS; ++h){ p[h] = __expf(p[h] - mx[h]); sm[h] = p[h]; }
    }
    if (deg > 64){
        for (int e = beg + 64 + lane; e < end; e += 64){
            int s = csrc[e];
#pragma unroll
            for (int h = 0; h < HEADS; ++h){
                float v = as1[(size_t)s*HEADS + h] + adh[h];
                v = v > 0.f ? v : SLOPE*v;
                sm[h] += __expf(v - mx[h]);
            }
        }
    }
    float inv[HEADS];
#pragma unroll
    for (int h = 0; h < HEADS; ++h){
        for (int o = 32; o; o >>= 1) sm[h] += __shfl_xor(sm[h], o);
        inv[h] = 1.f/(sm[h] + 1e-16f);
        p[h] = (lane < deg) ? p[h]*inv[h] : 0.f;
    }
    float acc1[HEADS], acc2[HEADS];
#pragma unroll
    for (int h = 0; h < HEADS; ++h){ acc1[h] = 0.f; acc2[h] = 0.f; }
    int cnt0 = deg < 64 ? deg : 64;
    for (int c0 = 0; c0 < cnt0; c0 += 16){
        float r1[16], r2[16];
#pragma unroll
        for (int i = 0; i < 16; ++i){
            int s = __shfl(s0, c0 + i);
            const float* xr = x + (size_t)s*FEAT;
            r1[i] = xr[lane];
            r2[i] = (lane < FEAT - 64) ? xr[64 + lane] : 0.f;
        }
#pragma unroll
        for (int i = 0; i < 16; ++i){
            if (c0 + i < cnt0){
#pragma unroll
                for (int h = 0; h < HEADS; ++h){
                    float al = __shfl(p[h], c0 + i);
                    acc1[h] += al*r1[i];
                    acc2[h] += al*r2[i];
                }
            }
        }
    }
    if (deg > 64){
        for (int base = beg + 64; base < end; base += 64){
            int cnt = min(64, end - base);
            int s1 = 0;
            float pp[HEADS];
#pragma unroll
            for (int h = 0; h < HEADS; ++h) pp[h] = 0.f;
            if (lane < cnt){
                s1 = csrc[base + lane];
#pragma unroll
                for (int h = 0; h < HEADS; ++h){
                    float v = as1[(size_t)s1*HEADS + h] + adh[h];
                    v = v > 0.f ? v : SLOPE*v;
                    pp[h] = __expf(v - mx[h])*inv[h];
                }
            }
            for (int c0 = 0; c0 < cnt; c0 += 16){
                float r1[16], r2[16];
#pragma unroll
                for (int i = 0; i < 16; ++i){
                    int s = __shfl(s1, c0 + i);
                    const float* xr = x + (size_t)s*FEAT;
                    r1[i] = xr[lane];
                    r2[i] = (lane < FEAT - 64) ? xr[64 + lane] : 0.f;
                }
#pragma unroll
                for (int i = 0; i < 16; ++i){
                    if (c0 + i < cnt){
#pragma unroll
                        for (int h = 0; h < HEADS; ++h){
                            float al = __shfl(pp[h], c0 + i);
                            acc1[h] += al*r1[i];
                            acc2[h] += al*r2[i];
                        }
                    }
                }
            }
        }
    }
#pragma unroll
    for (int h = 0; h < HEADS; ++h)
        aggh[(size_t)dst*D1 + h*FEAT + lane] = f2bf(acc1[h]);
    if (lane < FEAT - 64){
#pragma unroll
        for (int h = 0; h < HEADS; ++h)
            aggh[(size_t)dst*D1 + h*FEAT + 64 + lane] = f2bf(acc2[h]);
    }
}

// block = (head, node-tile-64): bf16 agg in, bf16 h1 out
__global__ __launch_bounds__(256) void k_post1(const ushort* __restrict__ aggh, const float* __restrict__ W1,
                                               const float* __restrict__ b1, ushort* __restrict__ h1h){
    __shared__ float w1s[FEAT][80];
    __shared__ float ags[64][81];
    __shared__ float bsh[FEAT];
    int ht = blockIdx.x >> 8;
    int nt = blockIdx.x & 255;
    int n0 = nt * 64;
    int t = threadIdx.x;
    for (int i = t; i < FEAT*FEAT; i += 256){
        int k = i / FEAT, j = i % FEAT;
        w1s[k][j] = W1[(size_t)k*D1 + ht*FEAT + j];
    }
    for (int i = t; i < 64*FEAT; i += 256){
        int r = i / FEAT, k = i % FEAT;
        ags[r][k] = bf2f(aggh[(size_t)(n0 + r)*D1 + ht*FEAT + k]);
    }
    if (t < FEAT) bsh[t] = b1[ht*FEAT + t];
    __syncthreads();
    if (t < 208){
        int rg = t / 13, cg = t % 13;
        int c0 = cg*6;
        float acc[4][6];
#pragma unroll
        for (int i = 0; i < 4; ++i)
#pragma unroll
            for (int j = 0; j < 6; ++j) acc[i][j] = 0.f;
        for (int k = 0; k < FEAT; ++k){
            float av[4];
#pragma unroll
            for (int i = 0; i < 4; ++i) av[i] = ags[rg*4 + i][k];
            float2 w01 = *(const float2*)&w1s[k][c0];
            float2 w23 = *(const float2*)&w1s[k][c0 + 2];
            float2 w45 = *(const float2*)&w1s[k][c0 + 4];
            float wv[6] = {w01.x, w01.y, w23.x, w23.y, w45.x, w45.y};
#pragma unroll
            for (int i = 0; i < 4; ++i)
#pragma unroll
                for (int j = 0; j < 6; ++j) acc[i][j] += av[i]*wv[j];
        }
#pragma unroll
        for (int i = 0; i < 4; ++i){
#pragma unroll
            for (int j = 0; j < 6; ++j){
                float v = acc[i][j] + bsh[c0 + j];
                v = v > 0.f ? v : __expf(v) - 1.f;   // ELU
                h1h[(size_t)(n0 + rg*4 + i)*D1 + ht*FEAT + c0 + j] = f2bf(v);
            }
        }
    }
}

// ---------------- GAT layer 2 GEMM via MFMA, fused alpha2 ----------------
__global__ __launch_bounds__(256) void k_gemm2m(const ushort* __restrict__ h1h, const float* __restrict__ w2,
                                                const float* __restrict__ s2w, const float* __restrict__ d2w,
                                                float* __restrict__ xl2,
                                                float* __restrict__ as2, float* __restrict__ ad2){
    __shared__ ushort As[64][40];
    __shared__ ushort Bs[128][40];
    int r0 = blockIdx.x * 64;
    int t = threadIdx.x;
    int w = t >> 6, l = t & 63;
    f32x4 acc[8];
#pragma unroll
    for (int i = 0; i < 8; ++i) acc[i] = (f32x4){0.f, 0.f, 0.f, 0.f};
    for (int k0 = 0; k0 < D1; k0 += 32){
        {
            int r = t >> 2, kq = (t & 3)*8;
            int gk = k0 + kq;
            ushort tmp[8];
            if (gk + 8 <= D1){
                *(ushort4*)&tmp[0] = *(const ushort4*)&h1h[(size_t)(r0 + r)*D1 + gk];
                *(ushort4*)&tmp[4] = *(const ushort4*)&h1h[(size_t)(r0 + r)*D1 + gk + 4];
            } else {
#pragma unroll
                for (int j = 0; j < 8; ++j)
                    tmp[j] = (gk + j < D1) ? h1h[(size_t)(r0 + r)*D1 + gk + j] : (ushort)0;
            }
            *(ushort4*)&As[r][kq]     = *(ushort4*)&tmp[0];
            *(ushort4*)&As[r][kq + 4] = *(ushort4*)&tmp[4];
        }
        {
            int n8 = (t & 15)*8, kk = t >> 4;
#pragma unroll
            for (int half = 0; half < 2; ++half){
                int k = kk + half*16;
                ushort tmp[8];
                if (k0 + k < D1){
                    float4 f0 = *(const float4*)&w2[(size_t)(k0 + k)*OD + n8];
                    float4 f1 = *(const float4*)&w2[(size_t)(k0 + k)*OD + n8 + 4];
                    tmp[0] = f2bf(f0.x); tmp[1] = f2bf(f0.y); tmp[2] = f2bf(f0.z); tmp[3] = f2bf(f0.w);
                    tmp[4] = f2bf(f1.x); tmp[5] = f2bf(f1.y); tmp[6] = f2bf(f1.z); tmp[7] = f2bf(f1.w);
                } else {
#pragma unroll
                    for (int j = 0; j < 8; ++j) tmp[j] = 0;
                }
#pragma unroll
                for (int j = 0; j < 8; ++j) Bs[n8 + j][k] = tmp[j];
            }
        }
        __syncthreads();
        short8 a = *(const short8*)&As[w*16 + (l & 15)][(l >> 4)*8];
#pragma unroll
        for (int nt = 0; nt < 8; ++nt){
            short8 b = *(const short8*)&Bs[nt*16 + (l & 15)][(l >> 4)*8];
            acc[nt] = __builtin_amdgcn_mfma_f32_16x16x32_bf16(a, b, acc[nt], 0, 0, 0);
        }
        __syncthreads();
    }
    int colg = l & 15, kg = l >> 4;
    float sa[4] = {0.f,0.f,0.f,0.f}, sd[4] = {0.f,0.f,0.f,0.f};
#pragma unroll
    for (int nt = 0; nt < 8; ++nt){
        int c = nt*16 + colg;
        float wsv = s2w[c], wdv = d2w[c];
#pragma unroll
        for (int r = 0; r < 4; ++r){
            float v = acc[nt][r];
            int row = r0 + w*16 + kg*4 + r;
            xl2[(size_t)row*OD + c] = v;
            sa[r] += v*wsv; sd[r] += v*wdv;
        }
    }
#pragma unroll
    for (int r = 0; r < 4; ++r){
#pragma unroll
        for (int o = 8; o; o >>= 1){ sa[r] += __shfl_xor(sa[r], o); sd[r] += __shfl_xor(sd[r], o); }
    }
    if (colg == 0){
        int row = r0 + w*16 + kg*4;
#pragma unroll
        for (int r = 0; r < 4; ++r){ as2[row + r] = sa[r]; ad2[row + r] = sd[r]; }
    }
}

// per dst (64-thread block): lane-owned alpha, chunk-staged f32 gather
__global__ __launch_bounds__(64) void k_gat2(const float* __restrict__ xl2, const float* __restrict__ as2,
                                             const float* __restrict__ ad2, const int* __restrict__ off,
                                             const int* __restrict__ csrc, const float* __restrict__ b2,
                                             float* __restrict__ h2){
    int dst = blockIdx.x, lane = threadIdx.x;
    int beg = off[dst], end = off[dst + 1];
    int deg = end - beg;
    float ad = ad2[dst];
    int s0 = 0; float v0 = -1e30f;
    if (lane < deg){
        s0 = csrc[beg + lane];
        float v = as2[s0] + ad;
        v0 = v > 0.f ? v : SLOPE*v;
    }
    float m = v0;
    if (deg > 64){
        for (int e = beg + 64 + lane; e < end; e += 64){
            float v = as2[csrc[e]] + ad; v = v > 0.f ? v : SLOPE*v;
            m = fmaxf(m, v);
        }
    }
    for (int o = 32; o; o >>= 1) m = fmaxf(m, __shfl_xor(m, o));
    float pe = (lane < deg) ? __expf(v0 - m) : 0.f;
    float sm = pe;
    if (deg > 64){
        for (int e = beg + 64 + lane; e < end; e += 64){
            float v = as2[csrc[e]] + ad; v = v > 0.f ? v : SLOPE*v;
            sm += __expf(v - m);
        }
    }
    for (int o = 32; o; o >>= 1) sm += __shfl_xor(sm, o);
    float inv = 1.f / (sm + 1e-16f);
    float p = pe * inv;
    float a0 = 0.f, a1 = 0.f;
    int cnt0 = deg < 64 ? deg : 64;
    for (int c0 = 0; c0 < cnt0; c0 += 16){
        float r1[16], r2[16];
#pragma unroll
        for (int i = 0; i < 16; ++i){
            int s = __shfl(s0, c0 + i);
            r1[i] = xl2[(size_t)s*OD + lane];
            r2[i] = xl2[(size_t)s*OD + 64 + lane];
        }
#pragma unroll
        for (int i = 0; i < 16; ++i){
            if (c0 + i < cnt0){
                float al = __shfl(p, c0 + i);
                a0 += al*r1[i];
                a1 += al*r2[i];
            }
        }
    }
    if (deg > 64){
        for (int base = beg + 64; base < end; base += 64){
            int cnt = min(64, end - base);
            int s1 = 0; float pp = 0.f;
            if (lane < cnt){
                s1 = csrc[base + lane];
                float v = as2[s1] + ad; v = v > 0.f ? v : SLOPE*v;
                pp = __expf(v - m) * inv;
            }
            for (int c0 = 0; c0 < cnt; c0 += 16){
                float r1[16], r2[16];
#pragma unroll
                for (int i = 0; i < 16; ++i){
                    int s = __shfl(s1, c0 + i);
                    r1[i] = xl2[(size_t)s*OD + lane];
                    r2[i] = xl2[(size_t)s*OD + 64 + lane];
                }
#pragma unroll
                for (int i = 0; i < 16; ++i){
                    if (c0 + i < cnt){
                        float al = __shfl(pp, c0 + i);
                        a0 += al*r1[i];
                        a1 += al*r2[i];
                    }
                }
            }
        }
    }
    float o0 = a0 + b2[lane];      o0 = o0 > 0.f ? o0 : 0.f;
    float o1 = a1 + b2[64 + lane]; o1 = o1 > 0.f ? o1 : 0.f;
    h2[(size_t)dst*OD + lane] = o0;
    h2[(size_t)dst*OD + 64 + lane] = o1;
}

// ---------------- protein branch ----------------
__global__ __launch_bounds__(256) void k_abuild(const int* __restrict__ target, const float* __restrict__ convw,
                                                float* __restrict__ Ag){
    __shared__ int Ai[VOC][256];
    __shared__ int tss[256];
    int b = blockIdx.x >> 2, seg = blockIdx.x & 3;
    int t = threadIdx.x;
#pragma unroll
    for (int v = 0; v < VOC; ++v) Ai[v][t] = 0;
    if (t < 250) tss[t] = target[b*PL + seg*250 + t];
    __syncthreads();
    const float* wp = convw + (size_t)(t >> 3)*(PL*8) + (size_t)(seg*250)*8 + (t & 7);
    const float SC = 16777216.0f;               // 2^24
    for (int i = 0; i < 250; ++i){
        float w = wp[(size_t)i*8];
        int q = __float2int_rn(w * SC);
        atomicAdd(&Ai[tss[i]][t], q);           // native ds_add_u32
    }
    __syncthreads();
    const float INV = 5.9604644775390625e-08f;  // 2^-24
    float* Ao = Ag + (size_t)blockIdx.x*VOC*256 + t;
#pragma unroll
    for (int v = 0; v < VOC; ++v) Ao[(size_t)v*256] = (float)Ai[v][t] * INV;
}

__global__ __launch_bounds__(256) void k_conv(const float* __restrict__ Ag, const float* __restrict__ emb,
                                              const float* __restrict__ convb, float* __restrict__ cbuf){
    __shared__ float As[VOC][128];
    __shared__ float embs[VOC*128 + 16];
    int b = blockIdx.x >> 1, half = blockIdx.x & 1;
    int t = threadIdx.x;
    for (int i = t; i < VOC*128; i += 256){
        int v = i >> 7, c = i & 127;
        float s = 0.f;
#pragma unroll
        for (int seg = 0; seg < 4; ++seg)
            s += Ag[((size_t)(b*4 + seg)*VOC + v)*256 + half*128 + c];
        As[v][c] = s;
        embs[i] = emb[i];
    }
    if (t < 16) embs[VOC*128 + t] = 0.f;
    __syncthreads();
    int o_l = t >> 4, pg = t & 15, p0 = pg * 8;
    float accp[8];
#pragma unroll
    for (int i = 0; i < 8; ++i) accp[i] = 0.f;
    for (int v = 0; v < VOC; ++v){
        float w[15];
        const float* er = embs + v*128 + p0;
#pragma unroll
        for (int i = 0; i < 15; ++i) w[i] = er[i];
#pragma unroll
        for (int k2 = 0; k2 < 8; ++k2){
            float a = As[v][o_l*8 + k2];
#pragma unroll
            for (int j = 0; j < 8; ++j) accp[j] += a * w[j + k2];
        }
    }
    float cbv = convb[half*16 + o_l];
#pragma unroll
    for (int j = 0; j < 8; ++j){
        int p = p0 + j;
        if (p < 121){
            float v2 = accp[j] + cbv;
            cbuf[(size_t)b*3872 + (half*16 + o_l)*121 + p] = v2 > 0.f ? v2 : 0.f;
        }
    }
}

__global__ __launch_bounds__(256) void k_xt(const float* __restrict__ cbuf, const float* __restrict__ fxw,
                                            float* __restrict__ xtp){
    __shared__ float csh[16][242];
    int kt = blockIdx.x >> 3, bt = blockIdx.x & 7;
    int t = threadIdx.x;
    for (int i = t; i < 16*242; i += 256){
        int bb = i / 242, kk = i % 242;
        csh[bb][kk] = cbuf[(size_t)(bt*16 + bb)*3872 + kt*242 + kk];
    }
    __syncthreads();
    int j = t & 127, bh = t >> 7;
    float acc[8];
#pragma unroll
    for (int i = 0; i < 8; ++i) acc[i] = 0.f;
    for (int kk = 0; kk < 242; ++kk){
        float w = fxw[(size_t)(kt*242 + kk)*128 + j];
#pragma unroll
        for (int bb = 0; bb < 8; ++bb) acc[bb] += csh[bh*8 + bb][kk] * w;
    }
#pragma unroll
    for (int bb = 0; bb < 8; ++bb)
        xtp[(size_t)kt*NB*128 + (size_t)(bt*16 + bh*8 + bb)*128 + j] = acc[bb];
}

// ---------------- head: fc1 with fused pool+fcg (512 blocks), fc2 partials, reduce+out ----------------
__global__ __launch_bounds__(256) void k_fc1(const float* __restrict__ h2, const int* __restrict__ batch,
                                             const float* __restrict__ fgw, const float* __restrict__ fgb,
                                             const float* __restrict__ xtp, const float* __restrict__ fxb,
                                             const float* __restrict__ w, const float* __restrict__ bias,
                                             float* __restrict__ out){
    __shared__ float row[OD];
    __shared__ float xc[256];
    int b = blockIdx.x >> 2, nt = blockIdx.x & 3;
    int t = threadIdx.x;
    int lo = 0, hi = NN;
    while (lo < hi){ int mid = (lo + hi) >> 1; if (batch[mid] < b) lo = mid + 1; else hi = mid; }
    int s0 = lo;
    lo = s0; hi = NN;
    while (lo < hi){ int mid = (lo + hi) >> 1; if (batch[mid] < b + 1) lo = mid + 1; else hi = mid; }
    int s1 = lo;
    if (t < 128){
        float mx = 0.f;
        for (int n = s0; n < s1; ++n) mx = fmaxf(mx, h2[(size_t)n*OD + t]);
        row[t] = mx;
    } else {
        int j = t - 128;
        float s = fxb[j];
#pragma unroll
        for (int kt = 0; kt < 16; ++kt) s += xtp[(size_t)kt*NB*128 + (size_t)b*128 + j];
        xc[t] = s;
    }
    __syncthreads();
    if (t < 128){
        float acc = 0.f;
        for (int k = 0; k < OD; ++k) acc += row[k] * fgw[k*OD + t];
        acc += fgb[t];
        xc[t] = acc > 0.f ? acc : 0.f;
    }
    __syncthreads();
    int j = nt*256 + t;
    float acc = 0.f;
    for (int k = 0; k < 256; ++k) acc += xc[k] * w[(size_t)k*1024 + j];
    acc += bias[j];
    out[b*1024 + j] = acc > 0.f ? acc : 0.f;
}

__global__ __launch_bounds__(256) void k_fc2p(const float* __restrict__ hf1, const float* __restrict__ w,
                                              float* __restrict__ part){
    __shared__ float row[256];
    int b = blockIdx.x >> 2, ks = blockIdx.x & 3;
    int t = threadIdx.x;
    row[t] = hf1[b*1024 + ks*256 + t];
    __syncthreads();
    float acc = 0.f;
    const float* wc = w + (size_t)(ks*256)*256 + t;
    for (int k = 0; k < 256; ++k) acc += row[k] * wc[(size_t)k*256];
    part[((size_t)ks*NB + b)*256 + t] = acc;
}

__global__ __launch_bounds__(256) void k_fc2red(const float* __restrict__ part, const float* __restrict__ bias,
                                                const float* __restrict__ ow, const float* __restrict__ ob,
                                                float* __restrict__ out){
    __shared__ float s2[256];
    int b = blockIdx.x, t = threadIdx.x;
    float v = part[(size_t)b*256 + t] + part[((size_t)NB + b)*256 + t]
            + part[((size_t)2*NB + b)*256 + t] + part[((size_t)3*NB + b)*256 + t];
    v += bias[t];
    v = v > 0.f ? v : 0.f;
    s2[t] = v * ow[t];
    __syncthreads();
    if (t < 64){
        float a = s2[t] + s2[t + 64] + s2[t + 128] + s2[t + 192];
#pragma unroll
        for (int o = 32; o; o >>= 1) a += __shfl_xor(a, o);
        if (t == 0) out[b] = a + ob[0];
    }
}

extern "C" void kernel_launch(void* const* d_in, const int* in_sizes, int n_in,
                              void* d_out, int out_size, void* d_ws, size_t ws_size,
                              hipStream_t stream){
    const float* x    = (const float*)d_in[0];
    const int*  ei    = (const int*)d_in[1];
    const int*  batch = (const int*)d_in[2];
    const int*  target= (const int*)d_in[3];
    const float* W1   = (const float*)d_in[4];
    const float* as1w = (const float*)d_in[5];
    const float* ad1w = (const float*)d_in[6];
    const float* b1   = (const float*)d_in[7];
    const float* W2   = (const float*)d_in[8];
    const float* as2w = (const float*)d_in[9];
    const float* ad2w = (const float*)d_in[10];
    const float* b2   = (const float*)d_in[11];
    const float* fgw  = (const float*)d_in[12];
    const float* fgb  = (const float*)d_in[13];
    const float* emb  = (const float*)d_in[14];
    const float* cw   = (const float*)d_in[15];
    const float* cb   = (const float*)d_in[16];
    const float* fxw  = (const float*)d_in[17];
    const float* fxb  = (const float*)d_in[18];
    const float* f1w  = (const float*)d_in[19];
    const float* f1b  = (const float*)d_in[20];
    const float* f2w  = (const float*)d_in[21];
    const float* f2b  = (const float*)d_in[22];
    const float* ow   = (const float*)d_in[23];
    const float* ob   = (const float*)d_in[24];

    float* f = (float*)d_ws;
    size_t o = 0;
    float* aggf = f + o; o += (size_t)NN*D1;    // bf16 agg (lower half used)
    float* h1f = f + o; o += (size_t)NN*D1;     // bf16 h1 (half used); reused as Ag after gemm2m
    float* as1 = f + o; o += (size_t)NN*HEADS;
    float* ad1 = f + o; o += (size_t)NN*HEADS;
    float* xl2 = f + o; o += (size_t)NN*OD;
    float* h2  = f + o; o += (size_t)NN*OD;
    float* as2 = f + o; o += NN;
    float* ad2 = f + o; o += NN;
    float* hf1 = f + o; o += NB*1024;
    float* part= f + o; o += (size_t)4*NB*256;
    float* cbuf= f + o; o += (size_t)NB*3872;
    float* xtp = f + o; o += (size_t)16*NB*128;
    int* cnt   = (int*)(f + o); o += NN;
    int* off   = (int*)(f + o); o += NN + 1;
    int* csrc  = (int*)(f + o); o += ET;
    ushort* aggh = (ushort*)aggf;
    ushort* h1h  = (ushort*)h1f;
    float*  Ag   = h1f;    // h1h dead after gemm2m; abuild launches after
    (void)ws_size; (void)in_sizes; (void)n_in; (void)out_size;

    // alpha1x first: independent of CSR, and its blocks 0..15 zero cnt (replaces memset)
    k_alpha1x<<<NN/64, 256, 0, stream>>>(x, W1, as1w, ad1w, as1, ad1, cnt);

    // CSR by destination (k_scan re-zeroes cnt for reuse as cursor)
    k_hist<<<(ET + 255)/256, 256, 0, stream>>>(ei, cnt);
    k_scan<<<1, 1024, 0, stream>>>(cnt, off);
    k_fill<<<(ET + 255)/256, 256, 0, stream>>>(ei, off, cnt, csrc);

    // GAT layer 1 aggregate + post
    k_gat1x<<<NN, 64, 0, stream>>>(x, as1, ad1, off, csrc, aggh);
    k_post1<<<HEADS*256, 256, 0, stream>>>(aggh, W1, b1, h1h);

    // GAT layer 2: MFMA GEMM + fused alpha2
    k_gemm2m<<<NN/64, 256, 0, stream>>>(h1h, W2, as2w, ad2w, xl2, as2, ad2);
    k_gat2<<<NN, 64, 0, stream>>>(xl2, as2, ad2, off, csrc, b2, h2);

    // protein branch
    k_abuild<<<NB*4, 256, 0, stream>>>(target, cw, Ag);
    k_conv<<<NB*2, 256, 0, stream>>>(Ag, emb, cb, cbuf);
    k_xt<<<128, 256, 0, stream>>>(cbuf, fxw, xtp);

    // head (pool+fcg fused into fc1)
    k_fc1<<<NB*4, 256, 0, stream>>>(h2, batch, fgw, fgb, xtp, fxb, f1w, f1b, hf1);
    k_fc2p<<<NB*4, 256, 0, stream>>>(hf1, f2w, part);
    k_fc2red<<<NB, 256, 0, stream>>>(part, f2b, ow, ob, (float*)d_out);
}